// Round 3
// baseline (2716.482 us; speedup 1.0000x reference)
//
#include <hip/hip_runtime.h>

// AlphaNet R6: spill-free two-pass recompute.
//   pass0: 2048 blocks x 32 samples, FULL sample rows staged contiguously in
//          LDS [32][486]. lane=(h<<5)|sample -> one wave_sum64 covers
//          (32 samples x 2 halves). Per-(ch,window) stats flushed IMMEDIATELY
//          (no persistent accumulator arrays; only m[<=20] per-half maxes).
//   k2_params / k2b: fold BN into w1 -> w1s[608][30], c0[30]
//   pass1: 1024 blocks x 64 samples, time-half staging (R5 structure, proven
//          math): recompute features, FMA into a[30] with wave-uniform s_load
//          w1s rows, LDS combine, relu dot w2 -> out.
// Both passes __launch_bounds__(256,1): empirically cap=256/arg -> cap 256;
// demand (~100 / ~120) fits, occupancy stays LDS-bound at 2 blocks/CU.
// ws floats: [0,304) stats | [304,608) params | [608,640) c0 | [640,18880) w1s

#define EPS_F    1e-8f
#define BN_EPS_F 1e-5f
#define P0PAD 486   // 32*486*4 = 62208 B; stride 486 -> <=4-way b64 aliasing
#define P1PAD 242

__device__ __forceinline__ float frcp(float x) {
  return __builtin_amdgcn_rcpf(x);
}

template<int Ctrl, int RowMask>
__device__ __forceinline__ float dpp_mov0(float v) {
  return __int_as_float(__builtin_amdgcn_update_dpp(
      0, __float_as_int(v), Ctrl, RowMask, 0xf, true));
}
// wave64 sum; result valid in lane 63. VALU-only.
__device__ __forceinline__ float wave_sum64(float v) {
  v += dpp_mov0<0x111, 0xf>(v);
  v += dpp_mov0<0x112, 0xf>(v);
  v += dpp_mov0<0x114, 0xf>(v);
  v += dpp_mov0<0x118, 0xf>(v);
  v += dpp_mov0<0x142, 0xa>(v);
  v += dpp_mov0<0x143, 0xc>(v);
  return v;
}

// pair p -> (i,j), p in triu(k=1) row-major order (matches IU/JU)
constexpr int PI_[28] = {0,0,0,0,0,0,0, 1,1,1,1,1,1, 2,2,2,2,2, 3,3,3,3, 4,4,4, 5,5, 6};
constexpr int PJ_[28] = {1,2,3,4,5,6,7, 2,3,4,5,6,7, 3,4,5,6,7, 4,5,6,7, 5,6,7, 6,7, 7};

// ---- immediate stat flushes (PASS 0) ----
__device__ __forceinline__ void flush_sq(float* __restrict__ stats, int ch,
                                         float v, int lane) {
  float t0 = wave_sum64(v);
  float t1 = wave_sum64(v * v);
  if (lane == 63) {
    atomicAdd(&stats[ch],      t0);
    atomicAdd(&stats[76 + ch], t1);
  }
}
__device__ __forceinline__ void flush_max(float* __restrict__ stats, int ch,
                                          float m, int lane) {
  float t2 = wave_sum64(m);
  float t3 = wave_sum64(m * m);
  if (lane == 63) {
    atomicAdd(&stats[152 + ch], t2);
    atomicAdd(&stats[228 + ch], t3);
  }
}

// ================= PASS 0 =================
// bx points at this lane's (sample,h) base: sx + sm*P0PAD + h*30

template<int W>
__device__ __forceinline__ void corr_p0(const float* __restrict__ bx,
                                        float* __restrict__ stats, int lane) {
  constexpr int PLO = W * 14;
  constexpr int FLO = W * 4;
  float m[18];
  #pragma unroll
  for (int k = 0; k < 18; ++k) m[k] = -3.0e38f;

  #pragma unroll
  for (int wl = 0; wl < 3; ++wl) {
    float sum[8], SD[8], SP[14];
    #pragma unroll
    for (int f = 0; f < 8; ++f) { sum[f] = 0.f; SD[f] = 0.f; }
    #pragma unroll
    for (int k = 0; k < 14; ++k) SP[k] = 0.f;
    #pragma unroll
    for (int tp = 0; tp < 5; ++tp) {
      float2 x2[8];
      #pragma unroll
      for (int f = 0; f < 8; ++f)
        x2[f] = *reinterpret_cast<const float2*>(bx + f*60 + wl*10 + tp*2);
      #pragma unroll
      for (int f = 0; f < 8; ++f) {
        sum[f] += x2[f].x + x2[f].y;
        SD[f] = fmaf(x2[f].x, x2[f].x, fmaf(x2[f].y, x2[f].y, SD[f]));
      }
      #pragma unroll
      for (int k = 0; k < 14; ++k) {
        const int i = PI_[PLO + k], j = PJ_[PLO + k];
        SP[k] = fmaf(x2[i].x, x2[j].x, fmaf(x2[i].y, x2[j].y, SP[k]));
      }
    }
    float mu[8], sd[8];
    #pragma unroll
    for (int f = 0; f < 8; ++f) {
      mu[f] = sum[f] * 0.1f;
      sd[f] = sqrtf(fmaf(-mu[f], mu[f], SD[f] * 0.1f) + EPS_F);
    }
    #pragma unroll
    for (int k = 0; k < 14; ++k) {
      const int i = PI_[PLO + k], j = PJ_[PLO + k];
      float cov = fmaf(-mu[i], mu[j], SP[k] * 0.1f);
      float v = cov * frcp(fmaf(sd[i], sd[j], EPS_F));
      m[k] = fmaxf(m[k], v);
      flush_sq(stats, PLO + k, v, lane);
    }
    #pragma unroll
    for (int q = 0; q < 4; ++q) {
      float v = mu[FLO + q] * frcp(sd[FLO + q] + EPS_F);
      m[14 + q] = fmaxf(m[14 + q], v);
      flush_sq(stats, 28 + FLO + q, v, lane);
    }
  }
  #pragma unroll
  for (int k = 0; k < 18; ++k) {
    const int ch = (k < 14) ? (PLO + k) : (28 + FLO + (k - 14));
    flush_max(stats, ch, m[k], lane);
  }
}

template<int G>
__device__ __forceinline__ void bc_p0(const float* __restrict__ bx,
                                      const float* __restrict__ cw,
                                      const float* __restrict__ cb,
                                      float* __restrict__ stats, int lane) {
  constexpr int FLO = G * 4;
  float m[20];
  #pragma unroll
  for (int k = 0; k < 20; ++k) m[k] = -3.0e38f;

  #pragma unroll
  for (int q = 0; q < 4; ++q) {
    const int f = FLO + q;
    #pragma unroll
    for (int wl = 0; wl < 3; ++wl) {
      float2 x2[5];
      #pragma unroll
      for (int tp = 0; tp < 5; ++tp)
        x2[tp] = *reinterpret_cast<const float2*>(bx + f*60 + wl*10 + tp*2);
      float wsm = 0.f;
      #pragma unroll
      for (int tp = 0; tp < 5; ++tp)
        wsm = fmaf(x2[tp].x, (float)(2*tp+1) * (1.f/55.f),
              fmaf(x2[tp].y, (float)(2*tp+2) * (1.f/55.f), wsm));
      m[q*5] = fmaxf(m[q*5], wsm);
      flush_sq(stats, 36 + f, wsm, lane);
      #pragma unroll
      for (int o = 0; o < 4; ++o) {
        float cv = cb[o];
        #pragma unroll
        for (int tp = 0; tp < 5; ++tp)
          cv = fmaf(x2[tp].x, cw[o*10 + 2*tp], fmaf(x2[tp].y, cw[o*10 + 2*tp + 1], cv));
        m[q*5 + 1 + o] = fmaxf(m[q*5 + 1 + o], cv);
        flush_sq(stats, 44 + o*8 + f, cv, lane);
      }
    }
  }
  #pragma unroll
  for (int k = 0; k < 20; ++k) {
    const int f = FLO + k/5, c = k%5;
    const int ch = (c == 0) ? (36 + f) : (44 + (c-1)*8 + f);
    flush_max(stats, ch, m[k], lane);
  }
}

__global__ void __launch_bounds__(256, 1)
pass0(const float* __restrict__ xb, const float* __restrict__ cw,
      const float* __restrict__ cb, float* __restrict__ stats) {
  __shared__ float sx[32 * P0PAD];
  const int tid  = threadIdx.x;
  const int wave = __builtin_amdgcn_readfirstlane(tid >> 6);
  const int lane = tid & 63;
  const int sm   = lane & 31;
  const int h    = lane >> 5;

  // stage 32 full sample rows, contiguous float2 (512 B per wave-load)
  const float* gb = xb + (size_t)blockIdx.x * (32 * 480);
  #pragma unroll
  for (int k = 0; k < 30; ++k) {
    const int g2  = k * 256 + tid;        // float2 index 0..7679
    const int smw = g2 / 240;
    const int c2  = g2 - smw * 240;
    const float2 t = *reinterpret_cast<const float2*>(gb + (size_t)g2 * 2);
    *reinterpret_cast<float2*>(sx + smw * P0PAD + c2 * 2) = t;
  }
  __syncthreads();

  const float* bx = sx + sm * P0PAD + h * 30;
  if      (wave == 0) corr_p0<0>(bx, stats, lane);
  else if (wave == 1) corr_p0<1>(bx, stats, lane);
  else if (wave == 2) bc_p0<0>(bx, cw, cb, stats, lane);
  else                bc_p0<1>(bx, cw, cb, stats, lane);
}

// ================= PASS 1 =================

template<int W>
__device__ __forceinline__ void corr_p1(const float* __restrict__ bx, int h,
                                        const float* __restrict__ w1s,
                                        float* __restrict__ a) {
  constexpr int PLO = W * 14;
  constexpr int FLO = W * 4;
  float m[18];
  #pragma unroll
  for (int k = 0; k < 18; ++k) m[k] = -3.0e38f;

  #pragma unroll
  for (int wl = 0; wl < 3; ++wl) {
    float sum[8], SD[8], SP[14];
    #pragma unroll
    for (int f = 0; f < 8; ++f) { sum[f] = 0.f; SD[f] = 0.f; }
    #pragma unroll
    for (int k = 0; k < 14; ++k) SP[k] = 0.f;
    #pragma unroll
    for (int tp = 0; tp < 5; ++tp) {
      float2 x2[8];
      #pragma unroll
      for (int f = 0; f < 8; ++f)
        x2[f] = *reinterpret_cast<const float2*>(bx + f*30 + wl*10 + tp*2);
      #pragma unroll
      for (int f = 0; f < 8; ++f) {
        sum[f] += x2[f].x + x2[f].y;
        SD[f] = fmaf(x2[f].x, x2[f].x, fmaf(x2[f].y, x2[f].y, SD[f]));
      }
      #pragma unroll
      for (int k = 0; k < 14; ++k) {
        const int i = PI_[PLO + k], j = PJ_[PLO + k];
        SP[k] = fmaf(x2[i].x, x2[j].x, fmaf(x2[i].y, x2[j].y, SP[k]));
      }
    }
    float mu[8], sd[8];
    #pragma unroll
    for (int f = 0; f < 8; ++f) {
      mu[f] = sum[f] * 0.1f;
      sd[f] = sqrtf(fmaf(-mu[f], mu[f], SD[f] * 0.1f) + EPS_F);
    }
    #pragma unroll
    for (int k = 0; k < 14; ++k) {
      const int i = PI_[PLO + k], j = PJ_[PLO + k];
      float cov = fmaf(-mu[i], mu[j], SP[k] * 0.1f);
      float v = cov * frcp(fmaf(sd[i], sd[j], EPS_F));
      m[k] = fmaxf(m[k], v);
      const float* wr = w1s + ((PLO + k)*6 + h*3 + wl) * 30;  // uniform -> s_load
      #pragma unroll
      for (int j2 = 0; j2 < 30; ++j2) a[j2] = fmaf(v, wr[j2], a[j2]);
    }
    #pragma unroll
    for (int q = 0; q < 4; ++q) {
      const int f = FLO + q;
      float v = mu[f] * frcp(sd[f] + EPS_F);
      m[14 + q] = fmaxf(m[14 + q], v);
      const float* wr = w1s + ((28 + f)*6 + h*3 + wl) * 30;
      #pragma unroll
      for (int j2 = 0; j2 < 30; ++j2) a[j2] = fmaf(v, wr[j2], a[j2]);
    }
  }
  #pragma unroll
  for (int k = 0; k < 18; ++k) {
    const int ch = (k < 14) ? (PLO + k) : (28 + FLO + (k - 14));
    const float* wr = w1s + (456 + ch*2 + h) * 30;
    #pragma unroll
    for (int j2 = 0; j2 < 30; ++j2) a[j2] = fmaf(m[k], wr[j2], a[j2]);
  }
}

template<int G>
__device__ __forceinline__ void bc_p1(const float* __restrict__ bx, int h,
                                      const float* __restrict__ cw,
                                      const float* __restrict__ cb,
                                      const float* __restrict__ w1s,
                                      float* __restrict__ a) {
  constexpr int FLO = G * 4;
  float m[20];
  #pragma unroll
  for (int k = 0; k < 20; ++k) m[k] = -3.0e38f;

  #pragma unroll
  for (int q = 0; q < 4; ++q) {
    const int f = FLO + q;
    #pragma unroll
    for (int wl = 0; wl < 3; ++wl) {
      float2 x2[5];
      #pragma unroll
      for (int tp = 0; tp < 5; ++tp)
        x2[tp] = *reinterpret_cast<const float2*>(bx + f*30 + wl*10 + tp*2);
      float wsm = 0.f;
      #pragma unroll
      for (int tp = 0; tp < 5; ++tp)
        wsm = fmaf(x2[tp].x, (float)(2*tp+1) * (1.f/55.f),
              fmaf(x2[tp].y, (float)(2*tp+2) * (1.f/55.f), wsm));
      m[q*5] = fmaxf(m[q*5], wsm);
      {
        const float* wr = w1s + ((36 + f)*6 + h*3 + wl) * 30;
        #pragma unroll
        for (int j2 = 0; j2 < 30; ++j2) a[j2] = fmaf(wsm, wr[j2], a[j2]);
      }
      #pragma unroll
      for (int o = 0; o < 4; ++o) {
        float cv = cb[o];
        #pragma unroll
        for (int tp = 0; tp < 5; ++tp)
          cv = fmaf(x2[tp].x, cw[o*10 + 2*tp], fmaf(x2[tp].y, cw[o*10 + 2*tp + 1], cv));
        m[q*5 + 1 + o] = fmaxf(m[q*5 + 1 + o], cv);
        const float* wr = w1s + ((44 + o*8 + f)*6 + h*3 + wl) * 30;
        #pragma unroll
        for (int j2 = 0; j2 < 30; ++j2) a[j2] = fmaf(cv, wr[j2], a[j2]);
      }
    }
  }
  #pragma unroll
  for (int k = 0; k < 20; ++k) {
    const int f = FLO + k/5, c = k%5;
    const int ch = (c == 0) ? (36 + f) : (44 + (c-1)*8 + f);
    const float* wr = w1s + (456 + ch*2 + h) * 30;
    #pragma unroll
    for (int j2 = 0; j2 < 30; ++j2) a[j2] = fmaf(m[k], wr[j2], a[j2]);
  }
}

__global__ void __launch_bounds__(256, 1)
pass1(const float* __restrict__ xb, const float* __restrict__ cw,
      const float* __restrict__ cb, const float* __restrict__ w1s,
      const float* __restrict__ c0, const float* __restrict__ w2,
      const float* __restrict__ b2, float* __restrict__ out) {
  __shared__ float sx[64 * P1PAD];
  const int tid  = threadIdx.x;
  const int wave = __builtin_amdgcn_readfirstlane(tid >> 6);
  const int lane = tid & 63;

  float a[30];
  #pragma unroll
  for (int j = 0; j < 30; ++j) a[j] = 0.f;

  const float* gb = xb + (size_t)blockIdx.x * (64 * 480);
  const float* bx = sx + lane * P1PAD;

  // shift/and staging decomposition (proven in R5):
  // i = k*256+tid; sm = 2k + (tid>>7), f = (tid>>4)&7, c = tid&15
  // (c==15: clamp global to c=14, dump LDS write to pad word 240)
  const int hi   = tid >> 7;
  const int fS   = (tid >> 4) & 7;
  const int cS   = tid & 15;
  const bool dmp = (cS == 15);
  const int cg   = dmp ? 14 : cS;
  const int lw   = hi * P1PAD + (dmp ? 240 : fS*30 + cS*2);

  #pragma unroll
  for (int h = 0; h < 2; ++h) {
    if (h) __syncthreads();        // all waves done reading previous half
    const int gw = hi*480 + fS*60 + h*30 + cg*2;
    #pragma unroll
    for (int k = 0; k < 32; ++k) {
      const float2 t = *reinterpret_cast<const float2*>(gb + k*960 + gw);
      *reinterpret_cast<float2*>(sx + k*(2*P1PAD) + lw) = t;
    }
    __syncthreads();
    if      (wave == 0) corr_p1<0>(bx, h, w1s, a);
    else if (wave == 1) corr_p1<1>(bx, h, w1s, a);
    else if (wave == 2) bc_p1<0>(bx, h, cw, cb, w1s, a);
    else                bc_p1<1>(bx, h, cw, cb, w1s, a);
  }

  __syncthreads();                 // all waves done with sx
  #pragma unroll
  for (int j = 0; j < 30; ++j) sx[tid*31 + j] = a[j];
  __syncthreads();
  if (tid < 64) {
    float t = b2[0];
    #pragma unroll
    for (int j = 0; j < 30; ++j) {
      float hh = ((sx[tid*31 + j] + sx[(64 + tid)*31 + j]) +
                  (sx[(128 + tid)*31 + j] + sx[(192 + tid)*31 + j])) + c0[j];
      t = fmaf(w2[j], fmaxf(hh, 0.f), t);
    }
    out[blockIdx.x * 64 + tid] = t;
  }
}

// ================= shared small kernels (unchanged) =================

__global__ void k2_params(const float* __restrict__ stats,
    const float* __restrict__ bn1g, const float* __restrict__ bn1b,
    const float* __restrict__ bn4g, const float* __restrict__ bn4b,
    const float* __restrict__ bn6g, const float* __restrict__ bn6b,
    const float* __restrict__ bn9g, const float* __restrict__ bn9b,
    const float* __restrict__ bnmg, const float* __restrict__ bnmb,
    float* __restrict__ params) {
  int c = threadIdx.x;
  if (c >= 76) return;
  float g, b;
  if      (c < 28) { g = bn1g[c];    b = bn1b[c];    }
  else if (c < 36) { g = bn4g[c-28]; b = bn4b[c-28]; }
  else if (c < 44) { g = bn6g[c-36]; b = bn6b[c-36]; }
  else             { g = bn9g[c-44]; b = bn9b[c-44]; }
  const float in1 = 1.0f / (65536.0f * 6.0f);
  const float in2 = 1.0f / (65536.0f * 2.0f);
  float mean = stats[c] * in1;
  float var  = stats[76 + c] * in1 - mean * mean;
  float r    = rsqrtf(var + BN_EPS_F);
  float sc1  = g * r;
  float sh1  = b - mean * sc1;
  float mmr  = stats[152 + c] * in2;
  float vmr  = stats[228 + c] * in2 - mmr * mmr;
  float meanm = sc1 * mmr + sh1;
  float varm  = sc1 * sc1 * vmr;
  float rm  = rsqrtf(varm + BN_EPS_F);
  float scm = bnmg[c] * rm;
  float shm = bnmb[c] - meanm * scm;
  params[c]        = sc1;
  params[76 + c]   = sh1;
  params[152 + c]  = scm;
  params[228 + c]  = shm;
}

__global__ void k2b(const float* __restrict__ w1, const float* __restrict__ params,
                    const float* __restrict__ b1, float* __restrict__ w1s,
                    float* __restrict__ c0) {
  int r = blockIdx.x;       // 0..607
  int j = threadIdx.x;      // j<30 active
  float sc, cst;
  if (r < 456) {
    int c = r / 6;
    sc = params[c]; cst = params[76 + c];
  } else {
    int c = (r - 456) >> 1;
    float sc1 = params[c], sh1 = params[76 + c];
    float scm = params[152 + c], shm = params[228 + c];
    sc = sc1 * scm; cst = fmaf(scm, sh1, shm);
  }
  if (j < 30) {
    float w = w1[j * 608 + r];
    w1s[r * 30 + j] = sc * w;
    float cadd = cst * w;
    if (r == 0) cadd += b1[j];
    atomicAdd(&c0[j], cadd);
  }
}

// ================= launch =================

extern "C" void kernel_launch(void* const* d_in, const int* in_sizes, int n_in,
                              void* d_out, int out_size, void* d_ws, size_t ws_size,
                              hipStream_t stream) {
  (void)in_sizes; (void)n_in; (void)out_size; (void)ws_size;
  const float* xb   = (const float*)d_in[0];
  const float* cw   = (const float*)d_in[1];
  const float* cb   = (const float*)d_in[2];
  const float* bn1g = (const float*)d_in[3];
  const float* bn1b = (const float*)d_in[4];
  const float* bn4g = (const float*)d_in[5];
  const float* bn4b = (const float*)d_in[6];
  const float* bn6g = (const float*)d_in[7];
  const float* bn6b = (const float*)d_in[8];
  const float* bn9g = (const float*)d_in[9];
  const float* bn9b = (const float*)d_in[10];
  const float* bnmg = (const float*)d_in[11];
  const float* bnmb = (const float*)d_in[12];
  const float* w1   = (const float*)d_in[13];
  const float* b1   = (const float*)d_in[14];
  const float* w2   = (const float*)d_in[15];
  const float* b2   = (const float*)d_in[16];

  float* out    = (float*)d_out;
  float* ws     = (float*)d_ws;
  float* stats  = ws;          // 304
  float* params = ws + 304;    // 304
  float* c0     = ws + 608;    // 32
  float* w1s    = ws + 640;    // 608*30

  hipMemsetAsync(ws, 0, 640 * sizeof(float), stream);
  pass0<<<2048, 256, 0, stream>>>(xb, cw, cb, stats);
  k2_params<<<1, 128, 0, stream>>>(stats, bn1g, bn1b, bn4g, bn4b, bn6g, bn6b,
                                   bn9g, bn9b, bnmg, bnmb, params);
  k2b<<<608, 64, 0, stream>>>(w1, params, b1, w1s, c0);
  pass1<<<1024, 256, 0, stream>>>(xb, cw, cb, w1s, c0, w2, b2, out);
}

// Round 4
// 576.242 us; speedup vs baseline: 4.7141x; 4.7141x over previous
//
#include <hip/hip_runtime.h>

// AlphaNet R7: atomic-free stats path.
//   pass0: 2048 blocks x 32 samples, full rows staged in LDS [32][486];
//          lane=(h<<5)|sample. Stats accumulated in REGISTERS per wave
//          (sacc/qacc/m, ~54 VGPR), ONE flush at block end -> per-block
//          partial sums written with plain stores to partial[304][2048].
//          ZERO global atomics (R6's 1.25M contended atomicAdds were the
//          2388us pathology: idle waves, VALUBusy 2.4%, HBM 0.5%).
//   kR:    304 blocks reduce partial rows -> stats (coalesced, no atomics).
//   k2_params: BN fold params (unchanged).
//   k2b:   w1s only (c0 atomics removed).
//   k2c:   c0[j] = b1[j] + sum_r cst_r*w1[j][r], wave-reduced, no atomics.
//   pass1: unchanged from R6 (time-half staging, wave-uniform s_load w1s).
// Both big passes __launch_bounds__(256,1) (cap 256, no spill; LDS-bound
// 2 blocks/CU).
// ws floats: [0,304) stats | [304,608) params | [608,640) c0 |
//            [640,18880) w1s | [18880, 18880+304*2048) partial

#define EPS_F    1e-8f
#define BN_EPS_F 1e-5f
#define P0PAD 486
#define P1PAD 242

__device__ __forceinline__ float frcp(float x) {
  return __builtin_amdgcn_rcpf(x);
}

template<int Ctrl, int RowMask>
__device__ __forceinline__ float dpp_mov0(float v) {
  return __int_as_float(__builtin_amdgcn_update_dpp(
      0, __float_as_int(v), Ctrl, RowMask, 0xf, true));
}
// wave64 sum; result valid in lane 63. VALU-only.
__device__ __forceinline__ float wave_sum64(float v) {
  v += dpp_mov0<0x111, 0xf>(v);
  v += dpp_mov0<0x112, 0xf>(v);
  v += dpp_mov0<0x114, 0xf>(v);
  v += dpp_mov0<0x118, 0xf>(v);
  v += dpp_mov0<0x142, 0xa>(v);
  v += dpp_mov0<0x143, 0xc>(v);
  return v;
}

// pair p -> (i,j), p in triu(k=1) row-major order (matches IU/JU)
constexpr int PI_[28] = {0,0,0,0,0,0,0, 1,1,1,1,1,1, 2,2,2,2,2, 3,3,3,3, 4,4,4, 5,5, 6};
constexpr int PJ_[28] = {1,2,3,4,5,6,7, 2,3,4,5,6,7, 3,4,5,6,7, 4,5,6,7, 5,6,7, 6,7, 7};

// ---- block-end partial flush: 4 wave-sums, lane-63 plain stores ----
__device__ __forceinline__ void flush_part(float* __restrict__ partial, int bid,
                                           int ch, float s, float q, float m,
                                           int lane) {
  float t0 = wave_sum64(s);
  float t1 = wave_sum64(q);
  float t2 = wave_sum64(m);
  float t3 = wave_sum64(m * m);
  if (lane == 63) {
    partial[(size_t)(      ch) * 2048 + bid] = t0;
    partial[(size_t)( 76 + ch) * 2048 + bid] = t1;
    partial[(size_t)(152 + ch) * 2048 + bid] = t2;
    partial[(size_t)(228 + ch) * 2048 + bid] = t3;
  }
}

// ================= PASS 0 =================
// bx = lane's (sample,h) base: sx + sm*P0PAD + h*30

template<int W>
__device__ __forceinline__ void corr_p0(const float* __restrict__ bx,
                                        float* __restrict__ partial,
                                        int bid, int lane) {
  constexpr int PLO = W * 14;
  constexpr int FLO = W * 4;
  float sacc[18], qacc[18], m[18];
  #pragma unroll
  for (int k = 0; k < 18; ++k) { sacc[k] = 0.f; qacc[k] = 0.f; m[k] = -3.0e38f; }

  #pragma unroll
  for (int wl = 0; wl < 3; ++wl) {
    float sum[8], SD[8], SP[14];
    #pragma unroll
    for (int f = 0; f < 8; ++f) { sum[f] = 0.f; SD[f] = 0.f; }
    #pragma unroll
    for (int k = 0; k < 14; ++k) SP[k] = 0.f;
    #pragma unroll
    for (int tp = 0; tp < 5; ++tp) {
      float2 x2[8];
      #pragma unroll
      for (int f = 0; f < 8; ++f)
        x2[f] = *reinterpret_cast<const float2*>(bx + f*60 + wl*10 + tp*2);
      #pragma unroll
      for (int f = 0; f < 8; ++f) {
        sum[f] += x2[f].x + x2[f].y;
        SD[f] = fmaf(x2[f].x, x2[f].x, fmaf(x2[f].y, x2[f].y, SD[f]));
      }
      #pragma unroll
      for (int k = 0; k < 14; ++k) {
        const int i = PI_[PLO + k], j = PJ_[PLO + k];
        SP[k] = fmaf(x2[i].x, x2[j].x, fmaf(x2[i].y, x2[j].y, SP[k]));
      }
    }
    float mu[8], sd[8];
    #pragma unroll
    for (int f = 0; f < 8; ++f) {
      mu[f] = sum[f] * 0.1f;
      sd[f] = sqrtf(fmaf(-mu[f], mu[f], SD[f] * 0.1f) + EPS_F);
    }
    #pragma unroll
    for (int k = 0; k < 14; ++k) {
      const int i = PI_[PLO + k], j = PJ_[PLO + k];
      float cov = fmaf(-mu[i], mu[j], SP[k] * 0.1f);
      float v = cov * frcp(fmaf(sd[i], sd[j], EPS_F));
      sacc[k] += v; qacc[k] = fmaf(v, v, qacc[k]); m[k] = fmaxf(m[k], v);
    }
    #pragma unroll
    for (int q = 0; q < 4; ++q) {
      float v = mu[FLO + q] * frcp(sd[FLO + q] + EPS_F);
      const int k = 14 + q;
      sacc[k] += v; qacc[k] = fmaf(v, v, qacc[k]); m[k] = fmaxf(m[k], v);
    }
  }
  #pragma unroll
  for (int k = 0; k < 18; ++k) {
    const int ch = (k < 14) ? (PLO + k) : (28 + FLO + (k - 14));
    flush_part(partial, bid, ch, sacc[k], qacc[k], m[k], lane);
  }
}

template<int G>
__device__ __forceinline__ void bc_p0(const float* __restrict__ bx,
                                      const float* __restrict__ cw,
                                      const float* __restrict__ cb,
                                      float* __restrict__ partial,
                                      int bid, int lane) {
  constexpr int FLO = G * 4;
  float sacc[20], qacc[20], m[20];
  #pragma unroll
  for (int k = 0; k < 20; ++k) { sacc[k] = 0.f; qacc[k] = 0.f; m[k] = -3.0e38f; }

  #pragma unroll
  for (int q = 0; q < 4; ++q) {
    const int f = FLO + q;
    #pragma unroll
    for (int wl = 0; wl < 3; ++wl) {
      float2 x2[5];
      #pragma unroll
      for (int tp = 0; tp < 5; ++tp)
        x2[tp] = *reinterpret_cast<const float2*>(bx + f*60 + wl*10 + tp*2);
      float wsm = 0.f;
      #pragma unroll
      for (int tp = 0; tp < 5; ++tp)
        wsm = fmaf(x2[tp].x, (float)(2*tp+1) * (1.f/55.f),
              fmaf(x2[tp].y, (float)(2*tp+2) * (1.f/55.f), wsm));
      {
        const int k = q*5;
        sacc[k] += wsm; qacc[k] = fmaf(wsm, wsm, qacc[k]); m[k] = fmaxf(m[k], wsm);
      }
      #pragma unroll
      for (int o = 0; o < 4; ++o) {
        float cv = cb[o];
        #pragma unroll
        for (int tp = 0; tp < 5; ++tp)
          cv = fmaf(x2[tp].x, cw[o*10 + 2*tp], fmaf(x2[tp].y, cw[o*10 + 2*tp + 1], cv));
        const int k = q*5 + 1 + o;
        sacc[k] += cv; qacc[k] = fmaf(cv, cv, qacc[k]); m[k] = fmaxf(m[k], cv);
      }
    }
  }
  #pragma unroll
  for (int k = 0; k < 20; ++k) {
    const int f = FLO + k/5, c = k%5;
    const int ch = (c == 0) ? (36 + f) : (44 + (c-1)*8 + f);
    flush_part(partial, bid, ch, sacc[k], qacc[k], m[k], lane);
  }
}

__global__ void __launch_bounds__(256, 1)
pass0(const float* __restrict__ xb, const float* __restrict__ cw,
      const float* __restrict__ cb, float* __restrict__ partial) {
  __shared__ float sx[32 * P0PAD];
  const int tid  = threadIdx.x;
  const int wave = __builtin_amdgcn_readfirstlane(tid >> 6);
  const int lane = tid & 63;
  const int sm   = lane & 31;
  const int h    = lane >> 5;
  const int bid  = blockIdx.x;

  // stage 32 full sample rows, contiguous float2
  const float* gb = xb + (size_t)bid * (32 * 480);
  #pragma unroll
  for (int k = 0; k < 30; ++k) {
    const int g2  = k * 256 + tid;        // float2 index 0..7679
    const int smw = g2 / 240;
    const int c2  = g2 - smw * 240;
    const float2 t = *reinterpret_cast<const float2*>(gb + (size_t)g2 * 2);
    *reinterpret_cast<float2*>(sx + smw * P0PAD + c2 * 2) = t;
  }
  __syncthreads();

  const float* bx = sx + sm * P0PAD + h * 30;
  if      (wave == 0) corr_p0<0>(bx, partial, bid, lane);
  else if (wave == 1) corr_p0<1>(bx, partial, bid, lane);
  else if (wave == 2) bc_p0<0>(bx, cw, cb, partial, bid, lane);
  else                bc_p0<1>(bx, cw, cb, partial, bid, lane);
}

// ---- reduce partial rows -> stats (no atomics) ----
__global__ void __launch_bounds__(256)
kR(const float* __restrict__ partial, float* __restrict__ stats) {
  const int r = blockIdx.x;
  const float* p = partial + (size_t)r * 2048;
  const int tid = threadIdx.x;
  float s = 0.f;
  #pragma unroll
  for (int i = 0; i < 8; ++i) s += p[i*256 + tid];
  s = wave_sum64(s);
  __shared__ float ls[4];
  if ((tid & 63) == 63) ls[tid >> 6] = s;
  __syncthreads();
  if (tid == 0) stats[r] = (ls[0] + ls[1]) + (ls[2] + ls[3]);
}

// ================= PASS 1 (unchanged from R6) =================

template<int W>
__device__ __forceinline__ void corr_p1(const float* __restrict__ bx, int h,
                                        const float* __restrict__ w1s,
                                        float* __restrict__ a) {
  constexpr int PLO = W * 14;
  constexpr int FLO = W * 4;
  float m[18];
  #pragma unroll
  for (int k = 0; k < 18; ++k) m[k] = -3.0e38f;

  #pragma unroll
  for (int wl = 0; wl < 3; ++wl) {
    float sum[8], SD[8], SP[14];
    #pragma unroll
    for (int f = 0; f < 8; ++f) { sum[f] = 0.f; SD[f] = 0.f; }
    #pragma unroll
    for (int k = 0; k < 14; ++k) SP[k] = 0.f;
    #pragma unroll
    for (int tp = 0; tp < 5; ++tp) {
      float2 x2[8];
      #pragma unroll
      for (int f = 0; f < 8; ++f)
        x2[f] = *reinterpret_cast<const float2*>(bx + f*30 + wl*10 + tp*2);
      #pragma unroll
      for (int f = 0; f < 8; ++f) {
        sum[f] += x2[f].x + x2[f].y;
        SD[f] = fmaf(x2[f].x, x2[f].x, fmaf(x2[f].y, x2[f].y, SD[f]));
      }
      #pragma unroll
      for (int k = 0; k < 14; ++k) {
        const int i = PI_[PLO + k], j = PJ_[PLO + k];
        SP[k] = fmaf(x2[i].x, x2[j].x, fmaf(x2[i].y, x2[j].y, SP[k]));
      }
    }
    float mu[8], sd[8];
    #pragma unroll
    for (int f = 0; f < 8; ++f) {
      mu[f] = sum[f] * 0.1f;
      sd[f] = sqrtf(fmaf(-mu[f], mu[f], SD[f] * 0.1f) + EPS_F);
    }
    #pragma unroll
    for (int k = 0; k < 14; ++k) {
      const int i = PI_[PLO + k], j = PJ_[PLO + k];
      float cov = fmaf(-mu[i], mu[j], SP[k] * 0.1f);
      float v = cov * frcp(fmaf(sd[i], sd[j], EPS_F));
      m[k] = fmaxf(m[k], v);
      const float* wr = w1s + ((PLO + k)*6 + h*3 + wl) * 30;  // uniform -> s_load
      #pragma unroll
      for (int j2 = 0; j2 < 30; ++j2) a[j2] = fmaf(v, wr[j2], a[j2]);
    }
    #pragma unroll
    for (int q = 0; q < 4; ++q) {
      const int f = FLO + q;
      float v = mu[f] * frcp(sd[f] + EPS_F);
      m[14 + q] = fmaxf(m[14 + q], v);
      const float* wr = w1s + ((28 + f)*6 + h*3 + wl) * 30;
      #pragma unroll
      for (int j2 = 0; j2 < 30; ++j2) a[j2] = fmaf(v, wr[j2], a[j2]);
    }
  }
  #pragma unroll
  for (int k = 0; k < 18; ++k) {
    const int ch = (k < 14) ? (PLO + k) : (28 + FLO + (k - 14));
    const float* wr = w1s + (456 + ch*2 + h) * 30;
    #pragma unroll
    for (int j2 = 0; j2 < 30; ++j2) a[j2] = fmaf(m[k], wr[j2], a[j2]);
  }
}

template<int G>
__device__ __forceinline__ void bc_p1(const float* __restrict__ bx, int h,
                                      const float* __restrict__ cw,
                                      const float* __restrict__ cb,
                                      const float* __restrict__ w1s,
                                      float* __restrict__ a) {
  constexpr int FLO = G * 4;
  float m[20];
  #pragma unroll
  for (int k = 0; k < 20; ++k) m[k] = -3.0e38f;

  #pragma unroll
  for (int q = 0; q < 4; ++q) {
    const int f = FLO + q;
    #pragma unroll
    for (int wl = 0; wl < 3; ++wl) {
      float2 x2[5];
      #pragma unroll
      for (int tp = 0; tp < 5; ++tp)
        x2[tp] = *reinterpret_cast<const float2*>(bx + f*30 + wl*10 + tp*2);
      float wsm = 0.f;
      #pragma unroll
      for (int tp = 0; tp < 5; ++tp)
        wsm = fmaf(x2[tp].x, (float)(2*tp+1) * (1.f/55.f),
              fmaf(x2[tp].y, (float)(2*tp+2) * (1.f/55.f), wsm));
      m[q*5] = fmaxf(m[q*5], wsm);
      {
        const float* wr = w1s + ((36 + f)*6 + h*3 + wl) * 30;
        #pragma unroll
        for (int j2 = 0; j2 < 30; ++j2) a[j2] = fmaf(wsm, wr[j2], a[j2]);
      }
      #pragma unroll
      for (int o = 0; o < 4; ++o) {
        float cv = cb[o];
        #pragma unroll
        for (int tp = 0; tp < 5; ++tp)
          cv = fmaf(x2[tp].x, cw[o*10 + 2*tp], fmaf(x2[tp].y, cw[o*10 + 2*tp + 1], cv));
        m[q*5 + 1 + o] = fmaxf(m[q*5 + 1 + o], cv);
        const float* wr = w1s + ((44 + o*8 + f)*6 + h*3 + wl) * 30;
        #pragma unroll
        for (int j2 = 0; j2 < 30; ++j2) a[j2] = fmaf(cv, wr[j2], a[j2]);
      }
    }
  }
  #pragma unroll
  for (int k = 0; k < 20; ++k) {
    const int f = FLO + k/5, c = k%5;
    const int ch = (c == 0) ? (36 + f) : (44 + (c-1)*8 + f);
    const float* wr = w1s + (456 + ch*2 + h) * 30;
    #pragma unroll
    for (int j2 = 0; j2 < 30; ++j2) a[j2] = fmaf(m[k], wr[j2], a[j2]);
  }
}

__global__ void __launch_bounds__(256, 1)
pass1(const float* __restrict__ xb, const float* __restrict__ cw,
      const float* __restrict__ cb, const float* __restrict__ w1s,
      const float* __restrict__ c0, const float* __restrict__ w2,
      const float* __restrict__ b2, float* __restrict__ out) {
  __shared__ float sx[64 * P1PAD];
  const int tid  = threadIdx.x;
  const int wave = __builtin_amdgcn_readfirstlane(tid >> 6);
  const int lane = tid & 63;

  float a[30];
  #pragma unroll
  for (int j = 0; j < 30; ++j) a[j] = 0.f;

  const float* gb = xb + (size_t)blockIdx.x * (64 * 480);
  const float* bx = sx + lane * P1PAD;

  const int hi   = tid >> 7;
  const int fS   = (tid >> 4) & 7;
  const int cS   = tid & 15;
  const bool dmp = (cS == 15);
  const int cg   = dmp ? 14 : cS;
  const int lw   = hi * P1PAD + (dmp ? 240 : fS*30 + cS*2);

  #pragma unroll
  for (int h = 0; h < 2; ++h) {
    if (h) __syncthreads();
    const int gw = hi*480 + fS*60 + h*30 + cg*2;
    #pragma unroll
    for (int k = 0; k < 32; ++k) {
      const float2 t = *reinterpret_cast<const float2*>(gb + k*960 + gw);
      *reinterpret_cast<float2*>(sx + k*(2*P1PAD) + lw) = t;
    }
    __syncthreads();
    if      (wave == 0) corr_p1<0>(bx, h, w1s, a);
    else if (wave == 1) corr_p1<1>(bx, h, w1s, a);
    else if (wave == 2) bc_p1<0>(bx, h, cw, cb, w1s, a);
    else                bc_p1<1>(bx, h, cw, cb, w1s, a);
  }

  __syncthreads();
  #pragma unroll
  for (int j = 0; j < 30; ++j) sx[tid*31 + j] = a[j];
  __syncthreads();
  if (tid < 64) {
    float t = b2[0];
    #pragma unroll
    for (int j = 0; j < 30; ++j) {
      float hh = ((sx[tid*31 + j] + sx[(64 + tid)*31 + j]) +
                  (sx[(128 + tid)*31 + j] + sx[(192 + tid)*31 + j])) + c0[j];
      t = fmaf(w2[j], fmaxf(hh, 0.f), t);
    }
    out[blockIdx.x * 64 + tid] = t;
  }
}

// ================= small kernels =================

__global__ void k2_params(const float* __restrict__ stats,
    const float* __restrict__ bn1g, const float* __restrict__ bn1b,
    const float* __restrict__ bn4g, const float* __restrict__ bn4b,
    const float* __restrict__ bn6g, const float* __restrict__ bn6b,
    const float* __restrict__ bn9g, const float* __restrict__ bn9b,
    const float* __restrict__ bnmg, const float* __restrict__ bnmb,
    float* __restrict__ params) {
  int c = threadIdx.x;
  if (c >= 76) return;
  float g, b;
  if      (c < 28) { g = bn1g[c];    b = bn1b[c];    }
  else if (c < 36) { g = bn4g[c-28]; b = bn4b[c-28]; }
  else if (c < 44) { g = bn6g[c-36]; b = bn6b[c-36]; }
  else             { g = bn9g[c-44]; b = bn9b[c-44]; }
  const float in1 = 1.0f / (65536.0f * 6.0f);
  const float in2 = 1.0f / (65536.0f * 2.0f);
  float mean = stats[c] * in1;
  float var  = stats[76 + c] * in1 - mean * mean;
  float r    = rsqrtf(var + BN_EPS_F);
  float sc1  = g * r;
  float sh1  = b - mean * sc1;
  float mmr  = stats[152 + c] * in2;
  float vmr  = stats[228 + c] * in2 - mmr * mmr;
  float meanm = sc1 * mmr + sh1;
  float varm  = sc1 * sc1 * vmr;
  float rm  = rsqrtf(varm + BN_EPS_F);
  float scm = bnmg[c] * rm;
  float shm = bnmb[c] - meanm * scm;
  params[c]        = sc1;
  params[76 + c]   = sh1;
  params[152 + c]  = scm;
  params[228 + c]  = shm;
}

__device__ __forceinline__ void row_scale(const float* __restrict__ params,
                                          int r, float& sc, float& cst) {
  if (r < 456) {
    int c = r / 6;
    sc = params[c]; cst = params[76 + c];
  } else {
    int c = (r - 456) >> 1;
    float sc1 = params[c], sh1 = params[76 + c];
    float scm = params[152 + c], shm = params[228 + c];
    sc = sc1 * scm; cst = fmaf(scm, sh1, shm);
  }
}

__global__ void k2b(const float* __restrict__ w1, const float* __restrict__ params,
                    float* __restrict__ w1s) {
  int r = blockIdx.x;       // 0..607
  int j = threadIdx.x;      // j<30 active
  float sc, cst;
  row_scale(params, r, sc, cst);
  if (j < 30) w1s[r * 30 + j] = sc * w1[j * 608 + r];
}

// c0[j] = b1[j] + sum_r cst_r * w1[j*608+r]   (30 blocks, wave-reduced)
__global__ void k2c(const float* __restrict__ w1, const float* __restrict__ params,
                    const float* __restrict__ b1, float* __restrict__ c0) {
  const int j = blockIdx.x;        // 0..29
  const int lane = threadIdx.x;    // 0..63
  float s = 0.f;
  for (int r = lane; r < 608; r += 64) {
    float sc, cst;
    row_scale(params, r, sc, cst);
    s = fmaf(cst, w1[j * 608 + r], s);
  }
  s = wave_sum64(s);
  if (lane == 63) c0[j] = s + b1[j];
}

// ================= launch =================

extern "C" void kernel_launch(void* const* d_in, const int* in_sizes, int n_in,
                              void* d_out, int out_size, void* d_ws, size_t ws_size,
                              hipStream_t stream) {
  (void)in_sizes; (void)n_in; (void)out_size; (void)ws_size;
  const float* xb   = (const float*)d_in[0];
  const float* cw   = (const float*)d_in[1];
  const float* cb   = (const float*)d_in[2];
  const float* bn1g = (const float*)d_in[3];
  const float* bn1b = (const float*)d_in[4];
  const float* bn4g = (const float*)d_in[5];
  const float* bn4b = (const float*)d_in[6];
  const float* bn6g = (const float*)d_in[7];
  const float* bn6b = (const float*)d_in[8];
  const float* bn9g = (const float*)d_in[9];
  const float* bn9b = (const float*)d_in[10];
  const float* bnmg = (const float*)d_in[11];
  const float* bnmb = (const float*)d_in[12];
  const float* w1   = (const float*)d_in[13];
  const float* b1   = (const float*)d_in[14];
  const float* w2   = (const float*)d_in[15];
  const float* b2   = (const float*)d_in[16];

  float* out     = (float*)d_out;
  float* ws      = (float*)d_ws;
  float* stats   = ws;          // 304
  float* params  = ws + 304;    // 304
  float* c0      = ws + 608;    // 32
  float* w1s     = ws + 640;    // 608*30
  float* partial = ws + 18880;  // 304*2048

  pass0<<<2048, 256, 0, stream>>>(xb, cw, cb, partial);
  kR<<<304, 256, 0, stream>>>(partial, stats);
  k2_params<<<1, 128, 0, stream>>>(stats, bn1g, bn1b, bn4g, bn4b, bn6g, bn6b,
                                   bn9g, bn9b, bnmg, bnmb, params);
  k2b<<<608, 32, 0, stream>>>(w1, params, w1s);
  k2c<<<30, 64, 0, stream>>>(w1, params, b1, c0);
  pass1<<<1024, 256, 0, stream>>>(xb, cw, cb, w1s, c0, w2, b2, out);
}

// Round 5
// 472.181 us; speedup vs baseline: 5.7531x; 1.2204x over previous
//
#include <hip/hip_runtime.h>

// AlphaNet R8: per-window staging, 4 blocks/CU, rolled code.
//   apass<0>: stats. 1024 blocks x 64 samples. Per window w=0..5: stage
//     [64][8f][10t] into LDS (21KB, stride 82 -> b64-conflict-free), sync,
//     wave-dispatch (corr<0>, corr<1>, bc G=0, bc G=1), sync. S/Q accumulate
//     in regs across windows (flush once at end); per-half maxes flushed at
//     w==2/5 into h-split slots of partial[304][2048]. Plain stores only.
//   kR: 304 blocks reduce partial -> stats.
//   k2_params/k2b/k2c: BN fold (k2b/k2c atomic-free, from R7).
//   apass<1>: same structure; FMA into a[30] with wave-uniform w1s rows,
//     2-stage LDS combine (fits 21KB), relu dot w2 -> out.
// __launch_bounds__(256,4): VGPR cap 128 (demand ~120-126), 16 waves/CU,
// grid 1024 = exactly 4 blocks/CU = 1 round. Rolled w-loop keeps code ~10KB.
// ws floats: [0,304) stats | [304,608) params | [608,640) c0 |
//            [640,18880) w1s | [18880,18880+304*2048) partial

#define EPS_F    1e-8f
#define BN_EPS_F 1e-5f
#define LSTR 82   // LDS floats per sample; even (b64 align), b64 banks: gcd(41,32)=1

__device__ __forceinline__ float frcp(float x) {
  return __builtin_amdgcn_rcpf(x);
}

template<int Ctrl, int RowMask>
__device__ __forceinline__ float dpp_mov0(float v) {
  return __int_as_float(__builtin_amdgcn_update_dpp(
      0, __float_as_int(v), Ctrl, RowMask, 0xf, true));
}
// wave64 sum; result valid in lane 63. VALU-only.
__device__ __forceinline__ float wave_sum64(float v) {
  v += dpp_mov0<0x111, 0xf>(v);
  v += dpp_mov0<0x112, 0xf>(v);
  v += dpp_mov0<0x114, 0xf>(v);
  v += dpp_mov0<0x118, 0xf>(v);
  v += dpp_mov0<0x142, 0xa>(v);
  v += dpp_mov0<0x143, 0xc>(v);
  return v;
}

// pair p -> (i,j), p in triu(k=1) row-major order (matches IU/JU)
constexpr int PI_[28] = {0,0,0,0,0,0,0, 1,1,1,1,1,1, 2,2,2,2,2, 3,3,3,3, 4,4,4, 5,5, 6};
constexpr int PJ_[28] = {1,2,3,4,5,6,7, 2,3,4,5,6,7, 3,4,5,6,7, 4,5,6,7, 5,6,7, 6,7, 7};

// ---- per-window corr subtask: 14 pairs [W*14,+14) + xb4 f [W*4,+4) ----
// state: S/Q (pass0, 18 used) or A (pass1, 30); M[18] per-half maxes.
template<int PASS, int W>
__device__ __forceinline__ void corr_step(
    const float* __restrict__ bx, const int w,
    const float* __restrict__ w1s,
    float* __restrict__ S, float* __restrict__ Q, float* __restrict__ M,
    float* __restrict__ A, float* __restrict__ partial,
    const int bid, const int lane)
{
  constexpr int PLO = W * 14;
  constexpr int FLO = W * 4;
  float sum[8], SD[8], SP[14];
  #pragma unroll
  for (int f = 0; f < 8; ++f) { sum[f] = 0.f; SD[f] = 0.f; }
  #pragma unroll
  for (int k = 0; k < 14; ++k) SP[k] = 0.f;
  #pragma unroll
  for (int tp = 0; tp < 5; ++tp) {
    float2 x2[8];
    #pragma unroll
    for (int f = 0; f < 8; ++f)
      x2[f] = *reinterpret_cast<const float2*>(bx + f*10 + tp*2);
    #pragma unroll
    for (int f = 0; f < 8; ++f) {
      sum[f] += x2[f].x + x2[f].y;
      SD[f] = fmaf(x2[f].x, x2[f].x, fmaf(x2[f].y, x2[f].y, SD[f]));
    }
    #pragma unroll
    for (int k = 0; k < 14; ++k) {
      const int i = PI_[PLO + k], j = PJ_[PLO + k];
      SP[k] = fmaf(x2[i].x, x2[j].x, fmaf(x2[i].y, x2[j].y, SP[k]));
    }
  }
  float mu[8], sd[8];
  #pragma unroll
  for (int f = 0; f < 8; ++f) {
    mu[f] = sum[f] * 0.1f;
    sd[f] = sqrtf(fmaf(-mu[f], mu[f], SD[f] * 0.1f) + EPS_F);
  }
  #pragma unroll
  for (int k = 0; k < 14; ++k) {
    const int i = PI_[PLO + k], j = PJ_[PLO + k];
    float cov = fmaf(-mu[i], mu[j], SP[k] * 0.1f);
    float v = cov * frcp(fmaf(sd[i], sd[j], EPS_F));
    M[k] = fmaxf(M[k], v);
    if (PASS == 0) { S[k] += v; Q[k] = fmaf(v, v, Q[k]); }
    else {
      const float* wr = w1s + ((PLO + k)*6 + w) * 30;   // uniform -> s_load
      #pragma unroll
      for (int j2 = 0; j2 < 30; ++j2) A[j2] = fmaf(v, wr[j2], A[j2]);
    }
  }
  #pragma unroll
  for (int q = 0; q < 4; ++q) {
    const int k = 14 + q;
    float v = mu[FLO + q] * frcp(sd[FLO + q] + EPS_F);
    M[k] = fmaxf(M[k], v);
    if (PASS == 0) { S[k] += v; Q[k] = fmaf(v, v, Q[k]); }
    else {
      const float* wr = w1s + ((28 + FLO + q)*6 + w) * 30;
      #pragma unroll
      for (int j2 = 0; j2 < 30; ++j2) A[j2] = fmaf(v, wr[j2], A[j2]);
    }
  }
  // end of half: consume + reset maxes
  if (w == 2 || w == 5) {
    const int h = (w == 5);
    #pragma unroll
    for (int k = 0; k < 18; ++k) {
      const int ch = (k < 14) ? (PLO + k) : (28 + FLO + (k - 14));
      if (PASS == 0) {
        float t2 = wave_sum64(M[k]);
        float t3 = wave_sum64(M[k] * M[k]);
        if (lane == 63) {
          partial[(size_t)(152 + ch) * 2048 + h*1024 + bid] = t2;
          partial[(size_t)(228 + ch) * 2048 + h*1024 + bid] = t3;
        }
      } else {
        const float* wr = w1s + (456 + ch*2 + h) * 30;
        #pragma unroll
        for (int j2 = 0; j2 < 30; ++j2) A[j2] = fmaf(M[k], wr[j2], A[j2]);
      }
      M[k] = -3.0e38f;
    }
  }
}

// ---- per-window bc subtask (runtime G): xb6 + conv for f [G*4,+4) ----
template<int PASS>
__device__ __forceinline__ void bc_step(
    const float* __restrict__ bx, const int w, const int G,
    const float* __restrict__ cw, const float* __restrict__ cb,
    const float* __restrict__ w1s,
    float* __restrict__ S, float* __restrict__ Q, float* __restrict__ M,
    float* __restrict__ A, float* __restrict__ partial,
    const int bid, const int lane)
{
  const int FLO = G * 4;
  #pragma unroll
  for (int q = 0; q < 4; ++q) {
    const int f = FLO + q;
    float2 x2[5];
    #pragma unroll
    for (int tp = 0; tp < 5; ++tp)
      x2[tp] = *reinterpret_cast<const float2*>(bx + f*10 + tp*2);
    float wsm = 0.f;
    #pragma unroll
    for (int tp = 0; tp < 5; ++tp)
      wsm = fmaf(x2[tp].x, (float)(2*tp+1) * (1.f/55.f),
            fmaf(x2[tp].y, (float)(2*tp+2) * (1.f/55.f), wsm));
    {
      const int k = q*5;
      M[k] = fmaxf(M[k], wsm);
      if (PASS == 0) { S[k] += wsm; Q[k] = fmaf(wsm, wsm, Q[k]); }
      else {
        const float* wr = w1s + ((36 + f)*6 + w) * 30;
        #pragma unroll
        for (int j2 = 0; j2 < 30; ++j2) A[j2] = fmaf(wsm, wr[j2], A[j2]);
      }
    }
    #pragma unroll
    for (int o = 0; o < 4; ++o) {
      float cv = cb[o];
      #pragma unroll
      for (int tp = 0; tp < 5; ++tp)
        cv = fmaf(x2[tp].x, cw[o*10 + 2*tp], fmaf(x2[tp].y, cw[o*10 + 2*tp + 1], cv));
      const int k = q*5 + 1 + o;
      M[k] = fmaxf(M[k], cv);
      if (PASS == 0) { S[k] += cv; Q[k] = fmaf(cv, cv, Q[k]); }
      else {
        const float* wr = w1s + ((44 + o*8 + f)*6 + w) * 30;
        #pragma unroll
        for (int j2 = 0; j2 < 30; ++j2) A[j2] = fmaf(cv, wr[j2], A[j2]);
      }
    }
  }
  if (w == 2 || w == 5) {
    const int h = (w == 5);
    #pragma unroll
    for (int k = 0; k < 20; ++k) {
      const int f = FLO + k/5, c = k%5;
      const int ch = (c == 0) ? (36 + f) : (44 + (c-1)*8 + f);
      if (PASS == 0) {
        float t2 = wave_sum64(M[k]);
        float t3 = wave_sum64(M[k] * M[k]);
        if (lane == 63) {
          partial[(size_t)(152 + ch) * 2048 + h*1024 + bid] = t2;
          partial[(size_t)(228 + ch) * 2048 + h*1024 + bid] = t3;
        }
      } else {
        const float* wr = w1s + (456 + ch*2 + h) * 30;
        #pragma unroll
        for (int j2 = 0; j2 < 30; ++j2) A[j2] = fmaf(M[k], wr[j2], A[j2]);
      }
      M[k] = -3.0e38f;
    }
  }
}

// ================= main passes =================

template<int PASS>
__global__ void __launch_bounds__(256, 4)
apass(const float* __restrict__ xb, const float* __restrict__ cw,
      const float* __restrict__ cb, const float* __restrict__ w1s,
      const float* __restrict__ c0, const float* __restrict__ w2,
      const float* __restrict__ b2, float* __restrict__ partial,
      float* __restrict__ out)
{
  __shared__ float sx[64 * LSTR];   // 21.0 KB
  const int tid  = threadIdx.x;
  const int wave = __builtin_amdgcn_readfirstlane(tid >> 6);
  const int lane = tid & 63;
  const int bid  = blockIdx.x;

  float A[30], S[20], Q[20], M[20];
  if (PASS == 0) {
    #pragma unroll
    for (int k = 0; k < 20; ++k) { S[k] = 0.f; Q[k] = 0.f; }
  } else {
    #pragma unroll
    for (int j = 0; j < 30; ++j) A[j] = 0.f;
  }
  #pragma unroll
  for (int k = 0; k < 20; ++k) M[k] = -3.0e38f;

  // staging: thread = (sample sq = tid>>2, quarter qq = tid&3);
  // per window 10 float2: f = 2*qq + k/5, t-pair = k%5
  const int sq = tid >> 2, qq = tid & 3;
  const float* gbase = xb + (size_t)bid * (64*480) + sq*480 + qq*120;
  float* lbase = sx + sq*LSTR + qq*20;
  const float* bx = sx + lane * LSTR;

  #pragma unroll 1
  for (int w = 0; w < 6; ++w) {
    // stage window w (global loads independent; ds_writes after)
    float2 t[10];
    #pragma unroll
    for (int k = 0; k < 10; ++k)
      t[k] = *reinterpret_cast<const float2*>(gbase + w*10 + (k/5)*60 + (k%5)*2);
    #pragma unroll
    for (int k = 0; k < 10; ++k)
      *reinterpret_cast<float2*>(lbase + (k/5)*10 + (k%5)*2) = t[k];
    __syncthreads();
    if      (wave == 0) corr_step<PASS,0>(bx, w, w1s, S, Q, M, A, partial, bid, lane);
    else if (wave == 1) corr_step<PASS,1>(bx, w, w1s, S, Q, M, A, partial, bid, lane);
    else                bc_step<PASS>(bx, w, wave - 2, cw, cb, w1s, S, Q, M, A,
                                      partial, bid, lane);
    __syncthreads();   // guards sx reads vs next window's staging writes
  }

  if (PASS == 0) {
    // one flush of sum/sumsq per owned channel (plain stores)
    const int nch = (wave < 2) ? 18 : 20;
    #pragma unroll
    for (int k = 0; k < 20; ++k) {
      if (k < nch) {
        int ch;
        if (wave < 2) ch = (k < 14) ? (wave*14 + k) : (28 + wave*4 + (k - 14));
        else {
          const int f = (wave - 2)*4 + k/5, c = k%5;
          ch = (c == 0) ? (36 + f) : (44 + (c-1)*8 + f);
        }
        float t0 = wave_sum64(S[k]);
        float t1 = wave_sum64(Q[k]);
        if (lane == 63) {
          partial[(size_t)ch * 2048 + bid]        = t0;
          partial[(size_t)(76 + ch) * 2048 + bid] = t1;
        }
      }
    }
  } else {
    // 2-stage combine in sx (needs 2*64*31*4 = 15.9 KB <= 21 KB)
    if (wave >= 2) {
      #pragma unroll
      for (int j = 0; j < 30; ++j) sx[((wave - 2)*64 + lane)*31 + j] = A[j];
    }
    __syncthreads();
    if (wave < 2) {
      #pragma unroll
      for (int j = 0; j < 30; ++j) A[j] += sx[(wave*64 + lane)*31 + j];
    }
    __syncthreads();
    if (wave == 1) {
      #pragma unroll
      for (int j = 0; j < 30; ++j) sx[lane*31 + j] = A[j];
    }
    __syncthreads();
    if (wave == 0) {
      float t = b2[0];
      #pragma unroll
      for (int j = 0; j < 30; ++j) {
        float hh = A[j] + sx[lane*31 + j] + c0[j];
        t = fmaf(w2[j], fmaxf(hh, 0.f), t);
      }
      out[bid * 64 + lane] = t;
    }
  }
}

// ---- reduce partial rows -> stats (no atomics) ----
__global__ void __launch_bounds__(256)
kR(const float* __restrict__ partial, float* __restrict__ stats) {
  const int r = blockIdx.x;
  const float* p = partial + (size_t)r * 2048;
  const int tid = threadIdx.x;
  float s = 0.f;
  #pragma unroll
  for (int i = 0; i < 8; ++i) s += p[i*256 + tid];
  s = wave_sum64(s);
  __shared__ float ls[4];
  if ((tid & 63) == 63) ls[tid >> 6] = s;
  __syncthreads();
  if (tid == 0) stats[r] = (ls[0] + ls[1]) + (ls[2] + ls[3]);
}

// ================= small kernels =================

__global__ void k2_params(const float* __restrict__ stats,
    const float* __restrict__ bn1g, const float* __restrict__ bn1b,
    const float* __restrict__ bn4g, const float* __restrict__ bn4b,
    const float* __restrict__ bn6g, const float* __restrict__ bn6b,
    const float* __restrict__ bn9g, const float* __restrict__ bn9b,
    const float* __restrict__ bnmg, const float* __restrict__ bnmb,
    float* __restrict__ params) {
  int c = threadIdx.x;
  if (c >= 76) return;
  float g, b;
  if      (c < 28) { g = bn1g[c];    b = bn1b[c];    }
  else if (c < 36) { g = bn4g[c-28]; b = bn4b[c-28]; }
  else if (c < 44) { g = bn6g[c-36]; b = bn6b[c-36]; }
  else             { g = bn9g[c-44]; b = bn9b[c-44]; }
  const float in1 = 1.0f / (65536.0f * 6.0f);
  const float in2 = 1.0f / (65536.0f * 2.0f);
  float mean = stats[c] * in1;
  float var  = stats[76 + c] * in1 - mean * mean;
  float r    = rsqrtf(var + BN_EPS_F);
  float sc1  = g * r;
  float sh1  = b - mean * sc1;
  float mmr  = stats[152 + c] * in2;
  float vmr  = stats[228 + c] * in2 - mmr * mmr;
  float meanm = sc1 * mmr + sh1;
  float varm  = sc1 * sc1 * vmr;
  float rm  = rsqrtf(varm + BN_EPS_F);
  float scm = bnmg[c] * rm;
  float shm = bnmb[c] - meanm * scm;
  params[c]        = sc1;
  params[76 + c]   = sh1;
  params[152 + c]  = scm;
  params[228 + c]  = shm;
}

__device__ __forceinline__ void row_scale(const float* __restrict__ params,
                                          int r, float& sc, float& cst) {
  if (r < 456) {
    int c = r / 6;
    sc = params[c]; cst = params[76 + c];
  } else {
    int c = (r - 456) >> 1;
    float sc1 = params[c], sh1 = params[76 + c];
    float scm = params[152 + c], shm = params[228 + c];
    sc = sc1 * scm; cst = fmaf(scm, sh1, shm);
  }
}

__global__ void k2b(const float* __restrict__ w1, const float* __restrict__ params,
                    float* __restrict__ w1s) {
  int r = blockIdx.x;       // 0..607
  int j = threadIdx.x;      // j<30 active
  float sc, cst;
  row_scale(params, r, sc, cst);
  if (j < 30) w1s[r * 30 + j] = sc * w1[j * 608 + r];
}

// c0[j] = b1[j] + sum_r cst_r * w1[j*608+r]   (30 blocks, wave-reduced)
__global__ void k2c(const float* __restrict__ w1, const float* __restrict__ params,
                    const float* __restrict__ b1, float* __restrict__ c0) {
  const int j = blockIdx.x;        // 0..29
  const int lane = threadIdx.x;    // 0..63
  float s = 0.f;
  for (int r = lane; r < 608; r += 64) {
    float sc, cst;
    row_scale(params, r, sc, cst);
    s = fmaf(cst, w1[j * 608 + r], s);
  }
  s = wave_sum64(s);
  if (lane == 63) c0[j] = s + b1[j];
}

// ================= launch =================

extern "C" void kernel_launch(void* const* d_in, const int* in_sizes, int n_in,
                              void* d_out, int out_size, void* d_ws, size_t ws_size,
                              hipStream_t stream) {
  (void)in_sizes; (void)n_in; (void)out_size; (void)ws_size;
  const float* xb   = (const float*)d_in[0];
  const float* cw   = (const float*)d_in[1];
  const float* cb   = (const float*)d_in[2];
  const float* bn1g = (const float*)d_in[3];
  const float* bn1b = (const float*)d_in[4];
  const float* bn4g = (const float*)d_in[5];
  const float* bn4b = (const float*)d_in[6];
  const float* bn6g = (const float*)d_in[7];
  const float* bn6b = (const float*)d_in[8];
  const float* bn9g = (const float*)d_in[9];
  const float* bn9b = (const float*)d_in[10];
  const float* bnmg = (const float*)d_in[11];
  const float* bnmb = (const float*)d_in[12];
  const float* w1   = (const float*)d_in[13];
  const float* b1   = (const float*)d_in[14];
  const float* w2   = (const float*)d_in[15];
  const float* b2   = (const float*)d_in[16];

  float* out     = (float*)d_out;
  float* ws      = (float*)d_ws;
  float* stats   = ws;          // 304
  float* params  = ws + 304;    // 304
  float* c0      = ws + 608;    // 32
  float* w1s     = ws + 640;    // 608*30
  float* partial = ws + 18880;  // 304*2048

  hipMemsetAsync(partial, 0, (size_t)304 * 2048 * sizeof(float), stream);
  apass<0><<<1024, 256, 0, stream>>>(xb, cw, cb, nullptr, nullptr, nullptr,
                                     nullptr, partial, nullptr);
  kR<<<304, 256, 0, stream>>>(partial, stats);
  k2_params<<<1, 128, 0, stream>>>(stats, bn1g, bn1b, bn4g, bn4b, bn6g, bn6b,
                                   bn9g, bn9b, bnmg, bnmb, params);
  k2b<<<608, 32, 0, stream>>>(w1, params, w1s);
  k2c<<<30, 64, 0, stream>>>(w1, params, b1, c0);
  apass<1><<<1024, 256, 0, stream>>>(xb, cw, cb, w1s, c0, w2, b2,
                                     nullptr, out);
}

// Round 6
// 406.848 us; speedup vs baseline: 6.6769x; 1.1606x over previous
//
#include <hip/hip_runtime.h>

// AlphaNet R9: R8 structure with the VGPR cap fixed.
//   Empirical launch-bounds law on this toolchain: cap ~= 256/w
//   (w=1 -> ~256, w=2 -> 128, w=4 -> 64). R8's (256,4) squeezed demand
//   (~115-120) into 64 VGPRs -> ~460MB/dispatch scratch spill (WRITE 222MB).
//   R9: __launch_bounds__(256,2) -> cap 128 >= demand, no spill; HW
//   occupancy still ~4 blocks/CU (VGPR 512/SIMD / 128 = 4 waves/SIMD,
//   LDS 21KB -> 7 blocks/CU).
//   apass<0>: stats. 1024 blocks x 64 samples. Per window w=0..5: stage
//     [64][8f][10t] into LDS (21KB, stride 82), sync, wave-dispatch
//     (corr<0>, corr<1>, bc G=0, bc G=1), sync. S/Q in regs across windows
//     (flush once); per-half maxes flushed at w==2/5 into h-split slots of
//     partial[304][2048]. Plain stores only, zero atomics.
//   kR: 304 blocks reduce partial -> stats.
//   k2_params/k2b/k2c: BN fold (atomic-free).
//   apass<1>: same structure; FMA into A[30] with wave-uniform s_load w1s
//     rows, 2-stage LDS combine, relu dot w2 -> out.
// ws floats: [0,304) stats | [304,608) params | [608,640) c0 |
//            [640,18880) w1s | [18880,18880+304*2048) partial

#define EPS_F    1e-8f
#define BN_EPS_F 1e-5f
#define LSTR 82   // LDS floats per sample; even (b64 align), gcd(41,32)=1

__device__ __forceinline__ float frcp(float x) {
  return __builtin_amdgcn_rcpf(x);
}

template<int Ctrl, int RowMask>
__device__ __forceinline__ float dpp_mov0(float v) {
  return __int_as_float(__builtin_amdgcn_update_dpp(
      0, __float_as_int(v), Ctrl, RowMask, 0xf, true));
}
// wave64 sum; result valid in lane 63. VALU-only.
__device__ __forceinline__ float wave_sum64(float v) {
  v += dpp_mov0<0x111, 0xf>(v);
  v += dpp_mov0<0x112, 0xf>(v);
  v += dpp_mov0<0x114, 0xf>(v);
  v += dpp_mov0<0x118, 0xf>(v);
  v += dpp_mov0<0x142, 0xa>(v);
  v += dpp_mov0<0x143, 0xc>(v);
  return v;
}

// pair p -> (i,j), p in triu(k=1) row-major order (matches IU/JU)
constexpr int PI_[28] = {0,0,0,0,0,0,0, 1,1,1,1,1,1, 2,2,2,2,2, 3,3,3,3, 4,4,4, 5,5, 6};
constexpr int PJ_[28] = {1,2,3,4,5,6,7, 2,3,4,5,6,7, 3,4,5,6,7, 4,5,6,7, 5,6,7, 6,7, 7};

// ---- per-window corr subtask: 14 pairs [W*14,+14) + xb4 f [W*4,+4) ----
template<int PASS, int W>
__device__ __forceinline__ void corr_step(
    const float* __restrict__ bx, const int w,
    const float* __restrict__ w1s,
    float* __restrict__ S, float* __restrict__ Q, float* __restrict__ M,
    float* __restrict__ A, float* __restrict__ partial,
    const int bid, const int lane)
{
  constexpr int PLO = W * 14;
  constexpr int FLO = W * 4;
  float sum[8], SD[8], SP[14];
  #pragma unroll
  for (int f = 0; f < 8; ++f) { sum[f] = 0.f; SD[f] = 0.f; }
  #pragma unroll
  for (int k = 0; k < 14; ++k) SP[k] = 0.f;
  #pragma unroll
  for (int tp = 0; tp < 5; ++tp) {
    float2 x2[8];
    #pragma unroll
    for (int f = 0; f < 8; ++f)
      x2[f] = *reinterpret_cast<const float2*>(bx + f*10 + tp*2);
    #pragma unroll
    for (int f = 0; f < 8; ++f) {
      sum[f] += x2[f].x + x2[f].y;
      SD[f] = fmaf(x2[f].x, x2[f].x, fmaf(x2[f].y, x2[f].y, SD[f]));
    }
    #pragma unroll
    for (int k = 0; k < 14; ++k) {
      const int i = PI_[PLO + k], j = PJ_[PLO + k];
      SP[k] = fmaf(x2[i].x, x2[j].x, fmaf(x2[i].y, x2[j].y, SP[k]));
    }
  }
  float mu[8], sd[8];
  #pragma unroll
  for (int f = 0; f < 8; ++f) {
    mu[f] = sum[f] * 0.1f;
    sd[f] = sqrtf(fmaf(-mu[f], mu[f], SD[f] * 0.1f) + EPS_F);
  }
  #pragma unroll
  for (int k = 0; k < 14; ++k) {
    const int i = PI_[PLO + k], j = PJ_[PLO + k];
    float cov = fmaf(-mu[i], mu[j], SP[k] * 0.1f);
    float v = cov * frcp(fmaf(sd[i], sd[j], EPS_F));
    M[k] = fmaxf(M[k], v);
    if (PASS == 0) { S[k] += v; Q[k] = fmaf(v, v, Q[k]); }
    else {
      const float* wr = w1s + ((PLO + k)*6 + w) * 30;   // uniform -> s_load
      #pragma unroll
      for (int j2 = 0; j2 < 30; ++j2) A[j2] = fmaf(v, wr[j2], A[j2]);
    }
  }
  #pragma unroll
  for (int q = 0; q < 4; ++q) {
    const int k = 14 + q;
    float v = mu[FLO + q] * frcp(sd[FLO + q] + EPS_F);
    M[k] = fmaxf(M[k], v);
    if (PASS == 0) { S[k] += v; Q[k] = fmaf(v, v, Q[k]); }
    else {
      const float* wr = w1s + ((28 + FLO + q)*6 + w) * 30;
      #pragma unroll
      for (int j2 = 0; j2 < 30; ++j2) A[j2] = fmaf(v, wr[j2], A[j2]);
    }
  }
  // end of half: consume + reset maxes
  if (w == 2 || w == 5) {
    const int h = (w == 5);
    #pragma unroll
    for (int k = 0; k < 18; ++k) {
      const int ch = (k < 14) ? (PLO + k) : (28 + FLO + (k - 14));
      if (PASS == 0) {
        float t2 = wave_sum64(M[k]);
        float t3 = wave_sum64(M[k] * M[k]);
        if (lane == 63) {
          partial[(size_t)(152 + ch) * 2048 + h*1024 + bid] = t2;
          partial[(size_t)(228 + ch) * 2048 + h*1024 + bid] = t3;
        }
      } else {
        const float* wr = w1s + (456 + ch*2 + h) * 30;
        #pragma unroll
        for (int j2 = 0; j2 < 30; ++j2) A[j2] = fmaf(M[k], wr[j2], A[j2]);
      }
      M[k] = -3.0e38f;
    }
  }
}

// ---- per-window bc subtask (runtime G): xb6 + conv for f [G*4,+4) ----
template<int PASS>
__device__ __forceinline__ void bc_step(
    const float* __restrict__ bx, const int w, const int G,
    const float* __restrict__ cw, const float* __restrict__ cb,
    const float* __restrict__ w1s,
    float* __restrict__ S, float* __restrict__ Q, float* __restrict__ M,
    float* __restrict__ A, float* __restrict__ partial,
    const int bid, const int lane)
{
  const int FLO = G * 4;
  #pragma unroll
  for (int q = 0; q < 4; ++q) {
    const int f = FLO + q;
    float2 x2[5];
    #pragma unroll
    for (int tp = 0; tp < 5; ++tp)
      x2[tp] = *reinterpret_cast<const float2*>(bx + f*10 + tp*2);
    float wsm = 0.f;
    #pragma unroll
    for (int tp = 0; tp < 5; ++tp)
      wsm = fmaf(x2[tp].x, (float)(2*tp+1) * (1.f/55.f),
            fmaf(x2[tp].y, (float)(2*tp+2) * (1.f/55.f), wsm));
    {
      const int k = q*5;
      M[k] = fmaxf(M[k], wsm);
      if (PASS == 0) { S[k] += wsm; Q[k] = fmaf(wsm, wsm, Q[k]); }
      else {
        const float* wr = w1s + ((36 + f)*6 + w) * 30;
        #pragma unroll
        for (int j2 = 0; j2 < 30; ++j2) A[j2] = fmaf(wsm, wr[j2], A[j2]);
      }
    }
    #pragma unroll
    for (int o = 0; o < 4; ++o) {
      float cv = cb[o];
      #pragma unroll
      for (int tp = 0; tp < 5; ++tp)
        cv = fmaf(x2[tp].x, cw[o*10 + 2*tp], fmaf(x2[tp].y, cw[o*10 + 2*tp + 1], cv));
      const int k = q*5 + 1 + o;
      M[k] = fmaxf(M[k], cv);
      if (PASS == 0) { S[k] += cv; Q[k] = fmaf(cv, cv, Q[k]); }
      else {
        const float* wr = w1s + ((44 + o*8 + f)*6 + w) * 30;
        #pragma unroll
        for (int j2 = 0; j2 < 30; ++j2) A[j2] = fmaf(cv, wr[j2], A[j2]);
      }
    }
  }
  if (w == 2 || w == 5) {
    const int h = (w == 5);
    #pragma unroll
    for (int k = 0; k < 20; ++k) {
      const int f = FLO + k/5, c = k%5;
      const int ch = (c == 0) ? (36 + f) : (44 + (c-1)*8 + f);
      if (PASS == 0) {
        float t2 = wave_sum64(M[k]);
        float t3 = wave_sum64(M[k] * M[k]);
        if (lane == 63) {
          partial[(size_t)(152 + ch) * 2048 + h*1024 + bid] = t2;
          partial[(size_t)(228 + ch) * 2048 + h*1024 + bid] = t3;
        }
      } else {
        const float* wr = w1s + (456 + ch*2 + h) * 30;
        #pragma unroll
        for (int j2 = 0; j2 < 30; ++j2) A[j2] = fmaf(M[k], wr[j2], A[j2]);
      }
      M[k] = -3.0e38f;
    }
  }
}

// ================= main passes =================

template<int PASS>
__global__ void __launch_bounds__(256, 2)
apass(const float* __restrict__ xb, const float* __restrict__ cw,
      const float* __restrict__ cb, const float* __restrict__ w1s,
      const float* __restrict__ c0, const float* __restrict__ w2,
      const float* __restrict__ b2, float* __restrict__ partial,
      float* __restrict__ out)
{
  __shared__ float sx[64 * LSTR];   // 21.0 KB
  const int tid  = threadIdx.x;
  const int wave = __builtin_amdgcn_readfirstlane(tid >> 6);
  const int lane = tid & 63;
  const int bid  = blockIdx.x;

  float A[30], S[20], Q[20], M[20];
  if (PASS == 0) {
    #pragma unroll
    for (int k = 0; k < 20; ++k) { S[k] = 0.f; Q[k] = 0.f; }
  } else {
    #pragma unroll
    for (int j = 0; j < 30; ++j) A[j] = 0.f;
  }
  #pragma unroll
  for (int k = 0; k < 20; ++k) M[k] = -3.0e38f;

  // staging: thread = (sample sq = tid>>2, quarter qq = tid&3);
  // per window 10 float2: f = 2*qq + k/5, t-pair = k%5
  const int sq = tid >> 2, qq = tid & 3;
  const float* gbase = xb + (size_t)bid * (64*480) + sq*480 + qq*120;
  float* lbase = sx + sq*LSTR + qq*20;
  const float* bx = sx + lane * LSTR;

  #pragma unroll 1
  for (int w = 0; w < 6; ++w) {
    // stage window w (global loads batched; ds_writes after)
    float2 t[10];
    #pragma unroll
    for (int k = 0; k < 10; ++k)
      t[k] = *reinterpret_cast<const float2*>(gbase + w*10 + (k/5)*60 + (k%5)*2);
    #pragma unroll
    for (int k = 0; k < 10; ++k)
      *reinterpret_cast<float2*>(lbase + (k/5)*10 + (k%5)*2) = t[k];
    __syncthreads();
    if      (wave == 0) corr_step<PASS,0>(bx, w, w1s, S, Q, M, A, partial, bid, lane);
    else if (wave == 1) corr_step<PASS,1>(bx, w, w1s, S, Q, M, A, partial, bid, lane);
    else                bc_step<PASS>(bx, w, wave - 2, cw, cb, w1s, S, Q, M, A,
                                      partial, bid, lane);
    __syncthreads();   // guards sx reads vs next window's staging writes
  }

  if (PASS == 0) {
    // one flush of sum/sumsq per owned channel (plain stores)
    const int nch = (wave < 2) ? 18 : 20;
    #pragma unroll
    for (int k = 0; k < 20; ++k) {
      if (k < nch) {
        int ch;
        if (wave < 2) ch = (k < 14) ? (wave*14 + k) : (28 + wave*4 + (k - 14));
        else {
          const int f = (wave - 2)*4 + k/5, c = k%5;
          ch = (c == 0) ? (36 + f) : (44 + (c-1)*8 + f);
        }
        float t0 = wave_sum64(S[k]);
        float t1 = wave_sum64(Q[k]);
        if (lane == 63) {
          partial[(size_t)ch * 2048 + bid]        = t0;
          partial[(size_t)(76 + ch) * 2048 + bid] = t1;
        }
      }
    }
  } else {
    // 2-stage combine in sx (needs 2*64*31*4 = 15.9 KB <= 21 KB)
    if (wave >= 2) {
      #pragma unroll
      for (int j = 0; j < 30; ++j) sx[((wave - 2)*64 + lane)*31 + j] = A[j];
    }
    __syncthreads();
    if (wave < 2) {
      #pragma unroll
      for (int j = 0; j < 30; ++j) A[j] += sx[(wave*64 + lane)*31 + j];
    }
    __syncthreads();
    if (wave == 1) {
      #pragma unroll
      for (int j = 0; j < 30; ++j) sx[lane*31 + j] = A[j];
    }
    __syncthreads();
    if (wave == 0) {
      float t = b2[0];
      #pragma unroll
      for (int j = 0; j < 30; ++j) {
        float hh = A[j] + sx[lane*31 + j] + c0[j];
        t = fmaf(w2[j], fmaxf(hh, 0.f), t);
      }
      out[bid * 64 + lane] = t;
    }
  }
}

// ---- reduce partial rows -> stats (no atomics) ----
__global__ void __launch_bounds__(256)
kR(const float* __restrict__ partial, float* __restrict__ stats) {
  const int r = blockIdx.x;
  const float* p = partial + (size_t)r * 2048;
  const int tid = threadIdx.x;
  float s = 0.f;
  #pragma unroll
  for (int i = 0; i < 8; ++i) s += p[i*256 + tid];
  s = wave_sum64(s);
  __shared__ float ls[4];
  if ((tid & 63) == 63) ls[tid >> 6] = s;
  __syncthreads();
  if (tid == 0) stats[r] = (ls[0] + ls[1]) + (ls[2] + ls[3]);
}

// ================= small kernels =================

__global__ void k2_params(const float* __restrict__ stats,
    const float* __restrict__ bn1g, const float* __restrict__ bn1b,
    const float* __restrict__ bn4g, const float* __restrict__ bn4b,
    const float* __restrict__ bn6g, const float* __restrict__ bn6b,
    const float* __restrict__ bn9g, const float* __restrict__ bn9b,
    const float* __restrict__ bnmg, const float* __restrict__ bnmb,
    float* __restrict__ params) {
  int c = threadIdx.x;
  if (c >= 76) return;
  float g, b;
  if      (c < 28) { g = bn1g[c];    b = bn1b[c];    }
  else if (c < 36) { g = bn4g[c-28]; b = bn4b[c-28]; }
  else if (c < 44) { g = bn6g[c-36]; b = bn6b[c-36]; }
  else             { g = bn9g[c-44]; b = bn9b[c-44]; }
  const float in1 = 1.0f / (65536.0f * 6.0f);
  const float in2 = 1.0f / (65536.0f * 2.0f);
  float mean = stats[c] * in1;
  float var  = stats[76 + c] * in1 - mean * mean;
  float r    = rsqrtf(var + BN_EPS_F);
  float sc1  = g * r;
  float sh1  = b - mean * sc1;
  float mmr  = stats[152 + c] * in2;
  float vmr  = stats[228 + c] * in2 - mmr * mmr;
  float meanm = sc1 * mmr + sh1;
  float varm  = sc1 * sc1 * vmr;
  float rm  = rsqrtf(varm + BN_EPS_F);
  float scm = bnmg[c] * rm;
  float shm = bnmb[c] - meanm * scm;
  params[c]        = sc1;
  params[76 + c]   = sh1;
  params[152 + c]  = scm;
  params[228 + c]  = shm;
}

__device__ __forceinline__ void row_scale(const float* __restrict__ params,
                                          int r, float& sc, float& cst) {
  if (r < 456) {
    int c = r / 6;
    sc = params[c]; cst = params[76 + c];
  } else {
    int c = (r - 456) >> 1;
    float sc1 = params[c], sh1 = params[76 + c];
    float scm = params[152 + c], shm = params[228 + c];
    sc = sc1 * scm; cst = fmaf(scm, sh1, shm);
  }
}

__global__ void k2b(const float* __restrict__ w1, const float* __restrict__ params,
                    float* __restrict__ w1s) {
  int r = blockIdx.x;       // 0..607
  int j = threadIdx.x;      // j<30 active
  float sc, cst;
  row_scale(params, r, sc, cst);
  if (j < 30) w1s[r * 30 + j] = sc * w1[j * 608 + r];
}

// c0[j] = b1[j] + sum_r cst_r * w1[j*608+r]   (30 blocks, wave-reduced)
__global__ void k2c(const float* __restrict__ w1, const float* __restrict__ params,
                    const float* __restrict__ b1, float* __restrict__ c0) {
  const int j = blockIdx.x;        // 0..29
  const int lane = threadIdx.x;    // 0..63
  float s = 0.f;
  for (int r = lane; r < 608; r += 64) {
    float sc, cst;
    row_scale(params, r, sc, cst);
    s = fmaf(cst, w1[j * 608 + r], s);
  }
  s = wave_sum64(s);
  if (lane == 63) c0[j] = s + b1[j];
}

// ================= launch =================

extern "C" void kernel_launch(void* const* d_in, const int* in_sizes, int n_in,
                              void* d_out, int out_size, void* d_ws, size_t ws_size,
                              hipStream_t stream) {
  (void)in_sizes; (void)n_in; (void)out_size; (void)ws_size;
  const float* xb   = (const float*)d_in[0];
  const float* cw   = (const float*)d_in[1];
  const float* cb   = (const float*)d_in[2];
  const float* bn1g = (const float*)d_in[3];
  const float* bn1b = (const float*)d_in[4];
  const float* bn4g = (const float*)d_in[5];
  const float* bn4b = (const float*)d_in[6];
  const float* bn6g = (const float*)d_in[7];
  const float* bn6b = (const float*)d_in[8];
  const float* bn9g = (const float*)d_in[9];
  const float* bn9b = (const float*)d_in[10];
  const float* bnmg = (const float*)d_in[11];
  const float* bnmb = (const float*)d_in[12];
  const float* w1   = (const float*)d_in[13];
  const float* b1   = (const float*)d_in[14];
  const float* w2   = (const float*)d_in[15];
  const float* b2   = (const float*)d_in[16];

  float* out     = (float*)d_out;
  float* ws      = (float*)d_ws;
  float* stats   = ws;          // 304
  float* params  = ws + 304;    // 304
  float* c0      = ws + 608;    // 32
  float* w1s     = ws + 640;    // 608*30
  float* partial = ws + 18880;  // 304*2048

  hipMemsetAsync(partial, 0, (size_t)304 * 2048 * sizeof(float), stream);
  apass<0><<<1024, 256, 0, stream>>>(xb, cw, cb, nullptr, nullptr, nullptr,
                                     nullptr, partial, nullptr);
  kR<<<304, 256, 0, stream>>>(partial, stats);
  k2_params<<<1, 128, 0, stream>>>(stats, bn1g, bn1b, bn4g, bn4b, bn6g, bn6b,
                                   bn9g, bn9b, bnmg, bnmb, params);
  k2b<<<608, 32, 0, stream>>>(w1, params, w1s);
  k2c<<<30, 64, 0, stream>>>(w1, params, b1, c0);
  apass<1><<<1024, 256, 0, stream>>>(xb, cw, cb, w1s, c0, w2, b2,
                                     nullptr, out);
}

// Round 7
// 398.890 us; speedup vs baseline: 6.8101x; 1.0200x over previous
//
#include <hip/hip_runtime.h>

// AlphaNet R10: R9 + async-stage prefetch + overhead trim.
//   apass<P>: 1024 blocks x 64 samples, per-window LDS staging (21KB).
//     NEW: window w+1's global loads issue BEFORE compute of window w
//     (register prefetch t[10]); ds_write after the post-compute barrier.
//     Staging latency hides under compute; LDS stays single-buffered.
//   partial layout (all slots written -> NO memset):
//     S rows  [0,76):   width 1024, idx ch*1024 + bid
//     Q rows  [76,152): width 1024
//     M rows: base 152*1024, width 2048: Msum ch -> ch*2048 + h*1024+bid,
//             Msq ch -> (76+ch)*2048 + h*1024 + bid
//   kR: 304 blocks, width-aware reduce -> stats (no atomics).
//   k2 (fused k2_params+k2b+k2c): 39 blocks; each recomputes BN params in
//     LDS (cheap, redundant), blocks 0..37 scale 16 w1 rows each,
//     block 38 computes c0 via 8-lane shfl reduce. Saves 2 launches.
//   Launches: apass0, kR, k2, apass1 (4 total; no memset).
// __launch_bounds__(256,2): cap 128 >= demand (~104 with prefetch).
// ws floats: [0,304) stats | [304,608) spare | [608,640) c0 |
//            [640,18880) w1s | [18880,+466944) partial

#define EPS_F    1e-8f
#define BN_EPS_F 1e-5f
#define LSTR 82   // LDS floats per sample; even (b64 align), gcd(41,32)=1

__device__ __forceinline__ float frcp(float x) {
  return __builtin_amdgcn_rcpf(x);
}

template<int Ctrl, int RowMask>
__device__ __forceinline__ float dpp_mov0(float v) {
  return __int_as_float(__builtin_amdgcn_update_dpp(
      0, __float_as_int(v), Ctrl, RowMask, 0xf, true));
}
// wave64 sum; result valid in lane 63. VALU-only.
__device__ __forceinline__ float wave_sum64(float v) {
  v += dpp_mov0<0x111, 0xf>(v);
  v += dpp_mov0<0x112, 0xf>(v);
  v += dpp_mov0<0x114, 0xf>(v);
  v += dpp_mov0<0x118, 0xf>(v);
  v += dpp_mov0<0x142, 0xa>(v);
  v += dpp_mov0<0x143, 0xc>(v);
  return v;
}

// pair p -> (i,j), p in triu(k=1) row-major order (matches IU/JU)
constexpr int PI_[28] = {0,0,0,0,0,0,0, 1,1,1,1,1,1, 2,2,2,2,2, 3,3,3,3, 4,4,4, 5,5, 6};
constexpr int PJ_[28] = {1,2,3,4,5,6,7, 2,3,4,5,6,7, 3,4,5,6,7, 4,5,6,7, 5,6,7, 6,7, 7};

// ---- per-window corr subtask: 14 pairs [W*14,+14) + xb4 f [W*4,+4) ----
template<int PASS, int W>
__device__ __forceinline__ void corr_step(
    const float* __restrict__ bx, const int w,
    const float* __restrict__ w1s,
    float* __restrict__ S, float* __restrict__ Q, float* __restrict__ M,
    float* __restrict__ A, float* __restrict__ partial,
    const int bid, const int lane)
{
  constexpr int PLO = W * 14;
  constexpr int FLO = W * 4;
  float sum[8], SD[8], SP[14];
  #pragma unroll
  for (int f = 0; f < 8; ++f) { sum[f] = 0.f; SD[f] = 0.f; }
  #pragma unroll
  for (int k = 0; k < 14; ++k) SP[k] = 0.f;
  #pragma unroll
  for (int tp = 0; tp < 5; ++tp) {
    float2 x2[8];
    #pragma unroll
    for (int f = 0; f < 8; ++f)
      x2[f] = *reinterpret_cast<const float2*>(bx + f*10 + tp*2);
    #pragma unroll
    for (int f = 0; f < 8; ++f) {
      sum[f] += x2[f].x + x2[f].y;
      SD[f] = fmaf(x2[f].x, x2[f].x, fmaf(x2[f].y, x2[f].y, SD[f]));
    }
    #pragma unroll
    for (int k = 0; k < 14; ++k) {
      const int i = PI_[PLO + k], j = PJ_[PLO + k];
      SP[k] = fmaf(x2[i].x, x2[j].x, fmaf(x2[i].y, x2[j].y, SP[k]));
    }
  }
  float mu[8], sd[8];
  #pragma unroll
  for (int f = 0; f < 8; ++f) {
    mu[f] = sum[f] * 0.1f;
    sd[f] = sqrtf(fmaf(-mu[f], mu[f], SD[f] * 0.1f) + EPS_F);
  }
  #pragma unroll
  for (int k = 0; k < 14; ++k) {
    const int i = PI_[PLO + k], j = PJ_[PLO + k];
    float cov = fmaf(-mu[i], mu[j], SP[k] * 0.1f);
    float v = cov * frcp(fmaf(sd[i], sd[j], EPS_F));
    M[k] = fmaxf(M[k], v);
    if (PASS == 0) { S[k] += v; Q[k] = fmaf(v, v, Q[k]); }
    else {
      const float* wr = w1s + ((PLO + k)*6 + w) * 30;   // uniform -> s_load
      #pragma unroll
      for (int j2 = 0; j2 < 30; ++j2) A[j2] = fmaf(v, wr[j2], A[j2]);
    }
  }
  #pragma unroll
  for (int q = 0; q < 4; ++q) {
    const int k = 14 + q;
    float v = mu[FLO + q] * frcp(sd[FLO + q] + EPS_F);
    M[k] = fmaxf(M[k], v);
    if (PASS == 0) { S[k] += v; Q[k] = fmaf(v, v, Q[k]); }
    else {
      const float* wr = w1s + ((28 + FLO + q)*6 + w) * 30;
      #pragma unroll
      for (int j2 = 0; j2 < 30; ++j2) A[j2] = fmaf(v, wr[j2], A[j2]);
    }
  }
  // end of half: consume + reset maxes
  if (w == 2 || w == 5) {
    const int h = (w == 5);
    #pragma unroll
    for (int k = 0; k < 18; ++k) {
      const int ch = (k < 14) ? (PLO + k) : (28 + FLO + (k - 14));
      if (PASS == 0) {
        float t2 = wave_sum64(M[k]);
        float t3 = wave_sum64(M[k] * M[k]);
        if (lane == 63) {
          partial[(size_t)(152*1024) + (size_t)ch * 2048 + h*1024 + bid] = t2;
          partial[(size_t)(152*1024) + (size_t)(76 + ch) * 2048 + h*1024 + bid] = t3;
        }
      } else {
        const float* wr = w1s + (456 + ch*2 + h) * 30;
        #pragma unroll
        for (int j2 = 0; j2 < 30; ++j2) A[j2] = fmaf(M[k], wr[j2], A[j2]);
      }
      M[k] = -3.0e38f;
    }
  }
}

// ---- per-window bc subtask (runtime G): xb6 + conv for f [G*4,+4) ----
template<int PASS>
__device__ __forceinline__ void bc_step(
    const float* __restrict__ bx, const int w, const int G,
    const float* __restrict__ cw, const float* __restrict__ cb,
    const float* __restrict__ w1s,
    float* __restrict__ S, float* __restrict__ Q, float* __restrict__ M,
    float* __restrict__ A, float* __restrict__ partial,
    const int bid, const int lane)
{
  const int FLO = G * 4;
  #pragma unroll
  for (int q = 0; q < 4; ++q) {
    const int f = FLO + q;
    float2 x2[5];
    #pragma unroll
    for (int tp = 0; tp < 5; ++tp)
      x2[tp] = *reinterpret_cast<const float2*>(bx + f*10 + tp*2);
    float wsm = 0.f;
    #pragma unroll
    for (int tp = 0; tp < 5; ++tp)
      wsm = fmaf(x2[tp].x, (float)(2*tp+1) * (1.f/55.f),
            fmaf(x2[tp].y, (float)(2*tp+2) * (1.f/55.f), wsm));
    {
      const int k = q*5;
      M[k] = fmaxf(M[k], wsm);
      if (PASS == 0) { S[k] += wsm; Q[k] = fmaf(wsm, wsm, Q[k]); }
      else {
        const float* wr = w1s + ((36 + f)*6 + w) * 30;
        #pragma unroll
        for (int j2 = 0; j2 < 30; ++j2) A[j2] = fmaf(wsm, wr[j2], A[j2]);
      }
    }
    #pragma unroll
    for (int o = 0; o < 4; ++o) {
      float cv = cb[o];
      #pragma unroll
      for (int tp = 0; tp < 5; ++tp)
        cv = fmaf(x2[tp].x, cw[o*10 + 2*tp], fmaf(x2[tp].y, cw[o*10 + 2*tp + 1], cv));
      const int k = q*5 + 1 + o;
      M[k] = fmaxf(M[k], cv);
      if (PASS == 0) { S[k] += cv; Q[k] = fmaf(cv, cv, Q[k]); }
      else {
        const float* wr = w1s + ((44 + o*8 + f)*6 + w) * 30;
        #pragma unroll
        for (int j2 = 0; j2 < 30; ++j2) A[j2] = fmaf(cv, wr[j2], A[j2]);
      }
    }
  }
  if (w == 2 || w == 5) {
    const int h = (w == 5);
    #pragma unroll
    for (int k = 0; k < 20; ++k) {
      const int f = FLO + k/5, c = k%5;
      const int ch = (c == 0) ? (36 + f) : (44 + (c-1)*8 + f);
      if (PASS == 0) {
        float t2 = wave_sum64(M[k]);
        float t3 = wave_sum64(M[k] * M[k]);
        if (lane == 63) {
          partial[(size_t)(152*1024) + (size_t)ch * 2048 + h*1024 + bid] = t2;
          partial[(size_t)(152*1024) + (size_t)(76 + ch) * 2048 + h*1024 + bid] = t3;
        }
      } else {
        const float* wr = w1s + (456 + ch*2 + h) * 30;
        #pragma unroll
        for (int j2 = 0; j2 < 30; ++j2) A[j2] = fmaf(M[k], wr[j2], A[j2]);
      }
      M[k] = -3.0e38f;
    }
  }
}

// ================= main passes =================

template<int PASS>
__global__ void __launch_bounds__(256, 2)
apass(const float* __restrict__ xb, const float* __restrict__ cw,
      const float* __restrict__ cb, const float* __restrict__ w1s,
      const float* __restrict__ c0, const float* __restrict__ w2,
      const float* __restrict__ b2, float* __restrict__ partial,
      float* __restrict__ out)
{
  __shared__ float sx[64 * LSTR];   // 21.0 KB
  const int tid  = threadIdx.x;
  const int wave = __builtin_amdgcn_readfirstlane(tid >> 6);
  const int lane = tid & 63;
  const int bid  = blockIdx.x;

  float A[30], S[20], Q[20], M[20];
  if (PASS == 0) {
    #pragma unroll
    for (int k = 0; k < 20; ++k) { S[k] = 0.f; Q[k] = 0.f; }
  } else {
    #pragma unroll
    for (int j = 0; j < 30; ++j) A[j] = 0.f;
  }
  #pragma unroll
  for (int k = 0; k < 20; ++k) M[k] = -3.0e38f;

  // staging: thread = (sample sq = tid>>2, quarter qq = tid&3);
  // per window 10 float2: f = 2*qq + k/5, t-pair = k%5
  const int sq = tid >> 2, qq = tid & 3;
  const float* gbase = xb + (size_t)bid * (64*480) + sq*480 + qq*120;
  float* lbase = sx + sq*LSTR + qq*20;
  const float* bx = sx + lane * LSTR;

  // prologue: stage window 0
  float2 t[10];
  #pragma unroll
  for (int k = 0; k < 10; ++k)
    t[k] = *reinterpret_cast<const float2*>(gbase + (k/5)*60 + (k%5)*2);
  #pragma unroll
  for (int k = 0; k < 10; ++k)
    *reinterpret_cast<float2*>(lbase + (k/5)*10 + (k%5)*2) = t[k];
  __syncthreads();

  #pragma unroll 1
  for (int w = 0; w < 6; ++w) {
    // async-stage split: issue next window's loads BEFORE compute of w
    if (w < 5) {
      #pragma unroll
      for (int k = 0; k < 10; ++k)
        t[k] = *reinterpret_cast<const float2*>(gbase + (w+1)*10 + (k/5)*60 + (k%5)*2);
    }
    if      (wave == 0) corr_step<PASS,0>(bx, w, w1s, S, Q, M, A, partial, bid, lane);
    else if (wave == 1) corr_step<PASS,1>(bx, w, w1s, S, Q, M, A, partial, bid, lane);
    else                bc_step<PASS>(bx, w, wave - 2, cw, cb, w1s, S, Q, M, A,
                                      partial, bid, lane);
    __syncthreads();   // all waves done reading window w
    if (w < 5) {
      #pragma unroll
      for (int k = 0; k < 10; ++k)
        *reinterpret_cast<float2*>(lbase + (k/5)*10 + (k%5)*2) = t[k];
      __syncthreads(); // window w+1 visible
    }
  }

  if (PASS == 0) {
    // one flush of sum/sumsq per owned channel (plain stores)
    const int nch = (wave < 2) ? 18 : 20;
    #pragma unroll
    for (int k = 0; k < 20; ++k) {
      if (k < nch) {
        int ch;
        if (wave < 2) ch = (k < 14) ? (wave*14 + k) : (28 + wave*4 + (k - 14));
        else {
          const int f = (wave - 2)*4 + k/5, c = k%5;
          ch = (c == 0) ? (36 + f) : (44 + (c-1)*8 + f);
        }
        float t0 = wave_sum64(S[k]);
        float t1 = wave_sum64(Q[k]);
        if (lane == 63) {
          partial[(size_t)ch * 1024 + bid]        = t0;
          partial[(size_t)(76 + ch) * 1024 + bid] = t1;
        }
      }
    }
  } else {
    // 2-stage combine in sx (needs 2*64*31*4 = 15.9 KB <= 21 KB)
    if (wave >= 2) {
      #pragma unroll
      for (int j = 0; j < 30; ++j) sx[((wave - 2)*64 + lane)*31 + j] = A[j];
    }
    __syncthreads();
    if (wave < 2) {
      #pragma unroll
      for (int j = 0; j < 30; ++j) A[j] += sx[(wave*64 + lane)*31 + j];
    }
    __syncthreads();
    if (wave == 1) {
      #pragma unroll
      for (int j = 0; j < 30; ++j) sx[lane*31 + j] = A[j];
    }
    __syncthreads();
    if (wave == 0) {
      float t0 = b2[0];
      #pragma unroll
      for (int j = 0; j < 30; ++j) {
        float hh = A[j] + sx[lane*31 + j] + c0[j];
        t0 = fmaf(w2[j], fmaxf(hh, 0.f), t0);
      }
      out[bid * 64 + lane] = t0;
    }
  }
}

// ---- reduce partial rows -> stats (width-aware, no atomics) ----
__global__ void __launch_bounds__(256)
kR(const float* __restrict__ partial, float* __restrict__ stats) {
  const int r = blockIdx.x;
  const int tid = threadIdx.x;
  float s = 0.f;
  if (r < 152) {
    const float* p = partial + (size_t)r * 1024;
    #pragma unroll
    for (int i = 0; i < 4; ++i) s += p[i*256 + tid];
  } else {
    const float* p = partial + (size_t)(152*1024) + (size_t)(r - 152) * 2048;
    #pragma unroll
    for (int i = 0; i < 8; ++i) s += p[i*256 + tid];
  }
  s = wave_sum64(s);
  __shared__ float ls[4];
  if ((tid & 63) == 63) ls[tid >> 6] = s;
  __syncthreads();
  if (tid == 0) stats[r] = (ls[0] + ls[1]) + (ls[2] + ls[3]);
}

// ================= fused BN-fold kernel =================
// 39 blocks: each recomputes BN params in LDS; blocks 0..37 scale 16 w1
// rows each into w1s; block 38 computes c0 (8-lane shfl reduce). No atomics.
__global__ void __launch_bounds__(256)
k2(const float* __restrict__ stats,
   const float* __restrict__ bn1g, const float* __restrict__ bn1b,
   const float* __restrict__ bn4g, const float* __restrict__ bn4b,
   const float* __restrict__ bn6g, const float* __restrict__ bn6b,
   const float* __restrict__ bn9g, const float* __restrict__ bn9b,
   const float* __restrict__ bnmg, const float* __restrict__ bnmb,
   const float* __restrict__ w1, const float* __restrict__ b1,
   float* __restrict__ w1s, float* __restrict__ c0) {
  __shared__ float P0[76], P1[76], P2[76], P3[76];
  const int tid = threadIdx.x;
  if (tid < 76) {
    const int c = tid;
    float g, b;
    if      (c < 28) { g = bn1g[c];    b = bn1b[c];    }
    else if (c < 36) { g = bn4g[c-28]; b = bn4b[c-28]; }
    else if (c < 44) { g = bn6g[c-36]; b = bn6b[c-36]; }
    else             { g = bn9g[c-44]; b = bn9b[c-44]; }
    const float in1 = 1.0f / (65536.0f * 6.0f);
    const float in2 = 1.0f / (65536.0f * 2.0f);
    float mean = stats[c] * in1;
    float var  = stats[76 + c] * in1 - mean * mean;
    float r    = rsqrtf(var + BN_EPS_F);
    float sc1  = g * r;
    float sh1  = b - mean * sc1;
    float mmr  = stats[152 + c] * in2;
    float vmr  = stats[228 + c] * in2 - mmr * mmr;
    float meanm = sc1 * mmr + sh1;
    float varm  = sc1 * sc1 * vmr;
    float rm  = rsqrtf(varm + BN_EPS_F);
    float scm = bnmg[c] * rm;
    float shm = bnmb[c] - meanm * scm;
    P0[c] = sc1; P1[c] = sh1; P2[c] = scm; P3[c] = shm;
  }
  __syncthreads();

  if (blockIdx.x < 38) {
    const int r0 = blockIdx.x * 16;
    for (int e = tid; e < 16*30; e += 256) {
      const int r = r0 + e / 30, j = e % 30;
      float sc;
      if (r < 456) sc = P0[r / 6];
      else { const int c = (r - 456) >> 1; sc = P0[c] * P2[c]; }
      w1s[r * 30 + j] = sc * w1[j * 608 + r];
    }
  } else {
    const int j = tid >> 3, l8 = tid & 7;
    if (j < 30) {
      float s = 0.f;
      for (int r = l8; r < 608; r += 8) {
        float cst;
        if (r < 456) cst = P1[r / 6];
        else {
          const int c = (r - 456) >> 1;
          cst = fmaf(P2[c], P1[c], P3[c]);
        }
        s = fmaf(cst, w1[j * 608 + r], s);
      }
      s += __shfl_xor(s, 1, 64);
      s += __shfl_xor(s, 2, 64);
      s += __shfl_xor(s, 4, 64);
      if (l8 == 0) c0[j] = s + b1[j];
    }
  }
}

// ================= launch =================

extern "C" void kernel_launch(void* const* d_in, const int* in_sizes, int n_in,
                              void* d_out, int out_size, void* d_ws, size_t ws_size,
                              hipStream_t stream) {
  (void)in_sizes; (void)n_in; (void)out_size; (void)ws_size;
  const float* xb   = (const float*)d_in[0];
  const float* cw   = (const float*)d_in[1];
  const float* cb   = (const float*)d_in[2];
  const float* bn1g = (const float*)d_in[3];
  const float* bn1b = (const float*)d_in[4];
  const float* bn4g = (const float*)d_in[5];
  const float* bn4b = (const float*)d_in[6];
  const float* bn6g = (const float*)d_in[7];
  const float* bn6b = (const float*)d_in[8];
  const float* bn9g = (const float*)d_in[9];
  const float* bn9b = (const float*)d_in[10];
  const float* bnmg = (const float*)d_in[11];
  const float* bnmb = (const float*)d_in[12];
  const float* w1   = (const float*)d_in[13];
  const float* b1   = (const float*)d_in[14];
  const float* w2   = (const float*)d_in[15];
  const float* b2   = (const float*)d_in[16];

  float* out     = (float*)d_out;
  float* ws      = (float*)d_ws;
  float* stats   = ws;          // 304
  float* c0      = ws + 608;    // 32
  float* w1s     = ws + 640;    // 608*30
  float* partial = ws + 18880;  // 152*1024 + 152*2048 = 466944

  apass<0><<<1024, 256, 0, stream>>>(xb, cw, cb, nullptr, nullptr, nullptr,
                                     nullptr, partial, nullptr);
  kR<<<304, 256, 0, stream>>>(partial, stats);
  k2<<<39, 256, 0, stream>>>(stats, bn1g, bn1b, bn4g, bn4b, bn6g, bn6b,
                             bn9g, bn9b, bnmg, bnmb, w1, b1, w1s, c0);
  apass<1><<<1024, 256, 0, stream>>>(xb, cw, cb, w1s, c0, w2, b2,
                                     nullptr, out);
}